// Round 5
// baseline (461.848 us; speedup 1.0000x reference)
//
#include <hip/hip_runtime.h>
#include <hip/hip_bf16.h>
#include <math.h>

#define S 2048
#define D 512
#define H 8
#define DH 64
#define F 2048
#define NLAYER 2
#define QKVLD 1536   // qkv buffer row stride (3*D)

typedef __attribute__((ext_vector_type(8))) short bf16x8;
typedef __attribute__((ext_vector_type(4))) float f32x4;
typedef __hip_bfloat16 bf16;

typedef __attribute__((address_space(3))) unsigned int lds_u32;
typedef __attribute__((address_space(1))) const unsigned int glb_u32;

__device__ __forceinline__ void gld16(const void* g, void* l) {
    __builtin_amdgcn_global_load_lds((glb_u32*)g, (lds_u32*)l, 16, 0, 0);
}

// ---------------- positional encoding add (fp32 + bf16 mirror) ----------------
__global__ void pos_add_kernel(const float* __restrict__ x, float* __restrict__ outF,
                               bf16* __restrict__ outB) {
    int idx = blockIdx.x * blockDim.x + threadIdx.x;
    if (idx >= S * D) return;
    int s = idx / D;
    int j = idx % D;
    int jj = (j < D / 2) ? j : j - D / 2;
    float rate = expf(-(float)jj * (logf(10000.0f) / (float)(D / 2)));
    float ang = (float)s * rate;
    float pe = (j < D / 2) ? sinf(ang) : cosf(ang);
    float v = x[idx] + pe;
    outF[idx] = v;
    outB[idx] = __float2bfloat16(v);
}

// ---------------- fp32 -> bf16 convert ----------------
__global__ void cvt_kernel(const float* __restrict__ in, bf16* __restrict__ out, int n) {
    int idx = blockIdx.x * blockDim.x + threadIdx.x;
    if (idx < n) out[idx] = __float2bfloat16(in[idx]);
}

// ---------------- batched transpose + convert ----------------
__global__ __launch_bounds__(256)
void transpose_cvt_b(const float* __restrict__ in, bf16* __restrict__ out, int R, int C,
                     size_t inStride, size_t outL, size_t outM, int mpl)
{
    __shared__ float t[64][65];
    const int z = blockIdx.z;
    const float* src = in + (size_t)z * inStride;
    bf16* dst = out + (size_t)(z / mpl) * outL + (size_t)(z % mpl) * outM;
    const int rb = blockIdx.x * 64, cb = blockIdx.y * 64;
    for (int i = threadIdx.x; i < 4096; i += 256) {
        int r = i >> 6, c = i & 63;
        t[r][c] = src[(size_t)(rb + r) * C + cb + c];
    }
    __syncthreads();
    for (int i = threadIdx.x; i < 4096; i += 256) {
        int r = i >> 6, c = i & 63;
        dst[(size_t)(cb + r) * R + rb + c] = __float2bfloat16(t[c][r]);
    }
}

// ---------------- V transpose: Vt[d][s] = QKV[s][1024 + d] ----------------
__global__ __launch_bounds__(256)
void vt_kernel(const bf16* __restrict__ qkv, bf16* __restrict__ vt)
{
    __shared__ short t[64][72];
    const int sb = blockIdx.x * 64;   // seq tile
    const int db = blockIdx.y * 64;   // d tile (0..511 across heads)
    for (int i = threadIdx.x; i < 512; i += 256) {
        int r = i >> 3, c8 = (i & 7) * 8;
        *(bf16x8*)&t[r][c8] = *(const bf16x8*)(qkv + (size_t)(sb + r) * QKVLD + 2 * D + db + c8);
    }
    __syncthreads();
    for (int i = threadIdx.x; i < 512; i += 256) {
        int d = i >> 3, s8 = (i & 7) * 8;
        bf16x8 v;
#pragma unroll
        for (int j = 0; j < 8; ++j) v[j] = t[s8 + j][d];
        *(bf16x8*)(vt + (size_t)(db + d) * S + sb + s8) = v;
    }
}

// ---------------- bf16 MFMA GEMM: out = A[M,K] @ Bt[N,K]^T + bias ----------------
template<int BM, int BN>
__global__ __launch_bounds__(256)
void gemm_bf16(const bf16* __restrict__ A, const bf16* __restrict__ Bt,
               const float* __restrict__ bias, float* __restrict__ outF,
               bf16* __restrict__ outB, int K, int ldc, int relu)
{
    constexpr int MI = BM / 32, NJ = BN / 32;
    __shared__ char lds[(BM + BN) * 64];
    const int tid = threadIdx.x;
    const int w = tid >> 6, l = tid & 63;
    const int l15 = l & 15, l4 = l >> 4;
    const int bm = blockIdx.y * BM, bn = blockIdx.x * BN;
    const int wr = (w >> 1) * (BM / 2), wc = (w & 1) * (BN / 2);

    f32x4 acc[MI][NJ] = {};
    const int sp = l & 3;          // physical 16B slot within 64B row

    for (int k0 = 0; k0 < K; k0 += 32) {
#pragma unroll
        for (int i = 0; i < BM / 64; ++i) {
            int row = w * (BM / 4) + i * 16 + (l >> 2);
            int sl = (sp ^ ((row >> 1) & 3)) * 8;
            gld16(A + (size_t)(bm + row) * K + k0 + sl, lds + (w * (BM / 4) + i * 16) * 64);
        }
#pragma unroll
        for (int i = 0; i < BN / 64; ++i) {
            int row = w * (BN / 4) + i * 16 + (l >> 2);
            int sl = (sp ^ ((row >> 1) & 3)) * 8;
            gld16(Bt + (size_t)(bn + row) * K + k0 + sl, lds + BM * 64 + (w * (BN / 4) + i * 16) * 64);
        }
        __syncthreads();
        bf16x8 af[MI], bfr[NJ];
#pragma unroll
        for (int i = 0; i < MI; ++i) {
            int row = wr + i * 16 + l15;
            af[i] = *(const bf16x8*)(lds + row * 64 + ((l4 ^ ((row >> 1) & 3)) << 4));
        }
#pragma unroll
        for (int j = 0; j < NJ; ++j) {
            int row = wc + j * 16 + l15;
            bfr[j] = *(const bf16x8*)(lds + BM * 64 + row * 64 + ((l4 ^ ((row >> 1) & 3)) << 4));
        }
#pragma unroll
        for (int i = 0; i < MI; ++i)
#pragma unroll
            for (int j = 0; j < NJ; ++j)
                acc[i][j] = __builtin_amdgcn_mfma_f32_16x16x32_bf16(af[i], bfr[j], acc[i][j], 0, 0, 0);
        __syncthreads();
    }

#pragma unroll
    for (int i = 0; i < MI; ++i)
#pragma unroll
        for (int j = 0; j < NJ; ++j)
#pragma unroll
            for (int q = 0; q < 4; ++q) {
                int row = bm + wr + i * 16 + l4 * 4 + q;
                int col = bn + wc + j * 16 + l15;
                float v = acc[i][j][q] + bias[col];
                if (relu) v = fmaxf(v, 0.f);
                if (outF) outF[(size_t)row * ldc + col] = v;
                if (outB) outB[(size_t)row * ldc + col] = __float2bfloat16(v);
            }
}

// ---------------- split-key MFMA flash attention, 128-key chunks ----------
// Block = 4 waves, one (head, q-tile of 16). Wave w handles 128-key chunks
// c ≡ w (mod 4). Swapped QK^T (mfma(K,Q)): lane l holds P for q = l&15.
// Q pre-scaled by 0.125*log2(e); softmax in log2 domain (exp2). Defer-max
// rescale (THR=8). Final flash-decoding merge of the 4 partials via LDS.
// Grid: (H, S/16)  -> x = head (XCD locality on K/V), y = q-tile.
template<int CAUSAL>
__global__ __launch_bounds__(256)
void attn_mfma4(const bf16* __restrict__ QKV, const bf16* __restrict__ Vt,
                bf16* __restrict__ O)
{
    // [0, 16384): per-wave P tiles (4096 each: 16 q x 128 keys bf16, XOR-swz)
    // [16384, 34304): merge region, 4 x 4480 (o 16x68 words + m 16 + l 16)
    __shared__ char lds[34304];
    const int tid = threadIdx.x;
    const int w = tid >> 6, l = tid & 63;
    const int l15 = l & 15, l4 = l >> 4;
    const int h = blockIdx.x, qt = blockIdx.y;
    const int qbase = qt * 16;
    const int qr = qbase + l15;
    char* plds = lds + w * 4096;

    // load Q fragment, pre-scaled by 0.125 * log2(e)
    const float QSC = 0.1803368801f;
    bf16x8 aq[2];
#pragma unroll
    for (int s = 0; s < 2; ++s) {
        bf16x8 raw = *(const bf16x8*)(QKV + (size_t)(qbase + l15) * QKVLD + h * DH + s * 32 + l4 * 8);
#pragma unroll
        for (int j = 0; j < 8; ++j) {
            float f = __builtin_bit_cast(float, ((unsigned int)(unsigned short)raw[j]) << 16) * QSC;
            raw[j] = __builtin_bit_cast(short, __float2bfloat16(f));
        }
        aq[s] = raw;
    }

    f32x4 o[4] = {};              // o[dt]: q = l4*4+reg, d = dt*16+l15
    float mrun = -1e30f, lrun = 0.f;

    const int cdiag = qt >> 3;                    // causal diagonal 128-chunk
    const int cmax = CAUSAL ? cdiag : (S / 128 - 1);
    for (int c = w; c <= cmax; c += 4) {
        const int kbase = c * 128;

        // S^T tiles: rows=keys, cols=q  (8 tiles of 16 keys)
        f32x4 st[8];
#pragma unroll
        for (int t = 0; t < 8; ++t) {
            f32x4 sacc = {0.f, 0.f, 0.f, 0.f};
#pragma unroll
            for (int s = 0; s < 2; ++s) {
                bf16x8 kf = *(const bf16x8*)(QKV + (size_t)(kbase + t * 16 + l15) * QKVLD
                                             + D + h * DH + s * 32 + l4 * 8);
                sacc = __builtin_amdgcn_mfma_f32_16x16x32_bf16(kf, aq[s], sacc, 0, 0, 0);
            }
            st[t] = sacc;
        }

        // mask + per-lane max over the 32 held values (all for q = l15)
        float mx = -1e30f;
#pragma unroll
        for (int t = 0; t < 8; ++t)
#pragma unroll
            for (int r = 0; r < 4; ++r) {
                float v = st[t][r];
                if (CAUSAL && c == cdiag) {
                    int key = kbase + t * 16 + l4 * 4 + r;
                    if (key > qr) v = -1e30f;
                }
                st[t][r] = v;
                mx = fmaxf(mx, v);
            }
        mx = fmaxf(mx, __shfl_xor(mx, 16));
        mx = fmaxf(mx, __shfl_xor(mx, 32));

        // defer-max: only rescale when max grew past threshold (log2 units)
        if (__any(mx > mrun + 8.0f)) {
            float mnew = fmaxf(mrun, mx);
            float scl = exp2f(mrun - mnew);
            mrun = mnew;
            lrun *= scl;
#pragma unroll
            for (int j = 0; j < 4; ++j) {
                float sj = __shfl(scl, (l & 48) | (l4 * 4 + j));
#pragma unroll
                for (int dt = 0; dt < 4; ++dt) o[dt][j] *= sj;
            }
        }

        float ps = 0.f;
#pragma unroll
        for (int t = 0; t < 8; ++t) {
            float e0 = exp2f(st[t][0] - mrun);
            float e1 = exp2f(st[t][1] - mrun);
            float e2 = exp2f(st[t][2] - mrun);
            float e3 = exp2f(st[t][3] - mrun);
            ps += (e0 + e1) + (e2 + e3);
            unsigned int lo = (unsigned int)(unsigned short)__builtin_bit_cast(short, __float2bfloat16(e0))
                            | ((unsigned int)(unsigned short)__builtin_bit_cast(short, __float2bfloat16(e1)) << 16);
            unsigned int hi = (unsigned int)(unsigned short)__builtin_bit_cast(short, __float2bfloat16(e2))
                            | ((unsigned int)(unsigned short)__builtin_bit_cast(short, __float2bfloat16(e3)) << 16);
            uint2 pk; pk.x = lo; pk.y = hi;
            int byte = (l15 * 256 + t * 32 + l4 * 8) ^ ((l15 & 7) << 4);
            *(uint2*)(plds + byte) = pk;
        }
        ps += __shfl_xor(ps, 16);
        ps += __shfl_xor(ps, 32);
        lrun += ps;

        // PV: A-frag from plds (row=q=l15, k=key), B-frag from Vt (contiguous)
        bf16x8 pf[4];
#pragma unroll
        for (int s = 0; s < 4; ++s) {
            int byte = (l15 * 256 + s * 64 + l4 * 16) ^ ((l15 & 7) << 4);
            pf[s] = *(const bf16x8*)(plds + byte);
        }
#pragma unroll
        for (int dt = 0; dt < 4; ++dt) {
#pragma unroll
            for (int s = 0; s < 4; ++s) {
                bf16x8 vf = *(const bf16x8*)(Vt + (size_t)(h * DH + dt * 16 + l15) * S
                                             + kbase + s * 32 + l4 * 8);
                o[dt] = __builtin_amdgcn_mfma_f32_16x16x32_bf16(pf[s], vf, o[dt], 0, 0, 0);
            }
        }
    }

    // ---- store partials ----
    const int wb = 16384 + w * 4480;
#pragma unroll
    for (int dt = 0; dt < 4; ++dt)
#pragma unroll
        for (int j = 0; j < 4; ++j)
            *(float*)(lds + wb + (((l4 * 4 + j) * 68) + dt * 16 + l15) * 4) = o[dt][j];
    if (l4 == 0) {
        *(float*)(lds + wb + 4352 + l15 * 4) = mrun;
        *(float*)(lds + wb + 4416 + l15 * 4) = lrun;
    }
    __syncthreads();

    // ---- merge 4 partials: thread t -> q = t>>4, d0 = (t&15)*4 (log2 domain) ----
    const int q = tid >> 4, d0 = (tid & 15) * 4;
    float mv[4], lv[4];
    float mt = -1e30f;
#pragma unroll
    for (int ww = 0; ww < 4; ++ww) {
        mv[ww] = *(float*)(lds + 16384 + ww * 4480 + 4352 + q * 4);
        lv[ww] = *(float*)(lds + 16384 + ww * 4480 + 4416 + q * 4);
        mt = fmaxf(mt, mv[ww]);
    }
    float lt = 0.f;
    float acc0 = 0.f, acc1 = 0.f, acc2 = 0.f, acc3 = 0.f;
#pragma unroll
    for (int ww = 0; ww < 4; ++ww) {
        float f = exp2f(mv[ww] - mt);
        lt += f * lv[ww];
        float4 ov = *(const float4*)(lds + 16384 + ww * 4480 + (q * 68 + d0) * 4);
        acc0 += f * ov.x; acc1 += f * ov.y; acc2 += f * ov.z; acc3 += f * ov.w;
    }
    float inv = 1.f / lt;
    bf16* op = O + (size_t)(qbase + q) * D + h * DH + d0;
    op[0] = __float2bfloat16(acc0 * inv);
    op[1] = __float2bfloat16(acc1 * inv);
    op[2] = __float2bfloat16(acc2 * inv);
    op[3] = __float2bfloat16(acc3 * inv);
}

// ---------------- residual add + layernorm (fp32, optional bf16 mirror) ----------------
__global__ __launch_bounds__(128)
void add_ln_kernel(const float* __restrict__ a, const float* __restrict__ b,
                   const float* __restrict__ g, const float* __restrict__ beta,
                   float* __restrict__ outF, bf16* __restrict__ outB)
{
    const int row = blockIdx.x;
    const int tid = threadIdx.x;
    float4 av = *(const float4*)&a[(size_t)row * D + tid * 4];
    float4 bv = *(const float4*)&b[(size_t)row * D + tid * 4];
    float4 s;
    s.x = av.x + bv.x; s.y = av.y + bv.y; s.z = av.z + bv.z; s.w = av.w + bv.w;
    float sum = s.x + s.y + s.z + s.w;
    float sq = s.x * s.x + s.y * s.y + s.z * s.z + s.w * s.w;
#pragma unroll
    for (int off = 32; off > 0; off >>= 1) {
        sum += __shfl_xor(sum, off);
        sq  += __shfl_xor(sq, off);
    }
    __shared__ float red[4];
    if ((tid & 63) == 0) { red[(tid >> 6) * 2] = sum; red[(tid >> 6) * 2 + 1] = sq; }
    __syncthreads();
    sum = red[0] + red[2];
    sq  = red[1] + red[3];
    float mu = sum / (float)D;
    float var = sq / (float)D - mu * mu;
    float rs = rsqrtf(var + 1e-6f);
    float4 gv = *(const float4*)&g[tid * 4];
    float4 bt = *(const float4*)&beta[tid * 4];
    float4 o;
    o.x = (s.x - mu) * rs * gv.x + bt.x;
    o.y = (s.y - mu) * rs * gv.y + bt.y;
    o.z = (s.z - mu) * rs * gv.z + bt.z;
    o.w = (s.w - mu) * rs * gv.w + bt.w;
    *(float4*)&outF[(size_t)row * D + tid * 4] = o;
    if (outB) {
        outB[(size_t)row * D + tid * 4 + 0] = __float2bfloat16(o.x);
        outB[(size_t)row * D + tid * 4 + 1] = __float2bfloat16(o.y);
        outB[(size_t)row * D + tid * 4 + 2] = __float2bfloat16(o.z);
        outB[(size_t)row * D + tid * 4 + 3] = __float2bfloat16(o.w);
    }
}

extern "C" void kernel_launch(void* const* d_in, const int* in_sizes, int n_in,
                              void* d_out, int out_size, void* d_ws, size_t ws_size,
                              hipStream_t stream)
{
    const float* x   = (const float*)d_in[0];
    const float* enc = (const float*)d_in[1];
    const float* a1w = (const float*)d_in[2];
    const float* a1b = (const float*)d_in[3];
    const float* a2w = (const float*)d_in[4];
    const float* a2b = (const float*)d_in[5];
    const float* fw1 = (const float*)d_in[6];
    const float* fb1 = (const float*)d_in[7];
    const float* fw2 = (const float*)d_in[8];
    const float* fb2 = (const float*)d_in[9];
    const float* lng = (const float*)d_in[10];
    const float* lnb = (const float*)d_in[11];
    float* out = (float*)d_out;

    char* wsb = (char*)d_ws;
    float* xb   = (float*)(wsb);                       // 4 MB
    float* ao   = (float*)(wsb + ((size_t)4 << 20));   // 4 MB
    bf16* xb16  = (bf16*)(wsb + ((size_t)8 << 20));    // 2 MB
    bf16* enc16 = (bf16*)(wsb + ((size_t)10 << 20));   // 2 MB
    bf16* att16 = (bf16*)(wsb + ((size_t)12 << 20));   // 2 MB
    bf16* qkv16 = (bf16*)(wsb + ((size_t)14 << 20));   // 6 MB [S][1536]
    bf16* vt16  = (bf16*)(wsb + ((size_t)20 << 20));   // 2 MB [512][S]
    bf16* ffh16 = qkv16;                               // 8 MB (overlaps vt16; disjoint lifetime)
    bf16* wts   = (bf16*)(wsb + ((size_t)22 << 20));   // 16 MB
    const size_t WCH = 1048576;
    const size_t DD = (size_t)D * D, DF = (size_t)D * F;

    // ---- weight prep (batched): transpose + bf16 ----
    transpose_cvt_b<<<dim3(8, 8, 8), 256, 0, stream>>>(a1w, wts,            D, D, DD, WCH, DD, 4);
    transpose_cvt_b<<<dim3(8, 8, 8), 256, 0, stream>>>(a2w, wts + 2 * WCH,  D, D, DD, WCH, DD, 4);
    transpose_cvt_b<<<dim3(8, 32, 2), 256, 0, stream>>>(fw1, wts + 4 * WCH, D, F, DF, WCH, 0, 1);
    transpose_cvt_b<<<dim3(32, 8, 2), 256, 0, stream>>>(fw2, wts + 6 * WCH, F, D, DF, WCH, 0, 1);
    cvt_kernel<<<(S * D + 255) / 256, 256, 0, stream>>>(enc, enc16, S * D);
    pos_add_kernel<<<(S * D + 255) / 256, 256, 0, stream>>>(x, xb, xb16);

    for (int l = 0; l < NLAYER; ++l) {
        const bf16* A1T = wts + (size_t)(0 + l) * WCH;
        const bf16* A2T = wts + (size_t)(2 + l) * WCH;
        const bf16* W1T = wts + (size_t)(4 + l) * WCH;
        const bf16* W2T = wts + (size_t)(6 + l) * WCH;
        const float* b1v = a1b + (size_t)l * 4 * D;
        const float* b2v = a2b + (size_t)l * 4 * D;

        // self-attention
        gemm_bf16<64, 64><<<dim3(24, 32), 256, 0, stream>>>(xb16, A1T, b1v, nullptr, qkv16, D, QKVLD, 0);
        vt_kernel<<<dim3(32, 8), 256, 0, stream>>>(qkv16, vt16);
        attn_mfma4<1><<<dim3(H, S / 16), 256, 0, stream>>>(qkv16, vt16, att16);
        gemm_bf16<64, 64><<<dim3(8, 32), 256, 0, stream>>>(att16, A1T + 3 * DD, b1v + 3 * D, ao, nullptr, D, D, 0);
        add_ln_kernel<<<S, 128, 0, stream>>>(xb, ao, lng + (size_t)(l * 3 + 0) * D, lnb + (size_t)(l * 3 + 0) * D, xb, xb16);

        // cross-attention
        gemm_bf16<64, 64><<<dim3(8, 32), 256, 0, stream>>>(xb16, A2T, b2v, nullptr, qkv16, D, QKVLD, 0);
        gemm_bf16<64, 64><<<dim3(16, 32), 256, 0, stream>>>(enc16, A2T + DD, b2v + D, nullptr, qkv16 + D, D, QKVLD, 0);
        vt_kernel<<<dim3(32, 8), 256, 0, stream>>>(qkv16, vt16);
        attn_mfma4<0><<<dim3(H, S / 16), 256, 0, stream>>>(qkv16, vt16, att16);
        gemm_bf16<64, 64><<<dim3(8, 32), 256, 0, stream>>>(att16, A2T + 3 * DD, b2v + 3 * D, ao, nullptr, D, D, 0);
        add_ln_kernel<<<S, 128, 0, stream>>>(xb, ao, lng + (size_t)(l * 3 + 1) * D, lnb + (size_t)(l * 3 + 1) * D, xb, xb16);

        // FFN
        gemm_bf16<128, 128><<<dim3(16, 16), 256, 0, stream>>>(xb16, W1T, fb1 + (size_t)l * F, nullptr, ffh16, D, F, 1);
        gemm_bf16<64, 64><<<dim3(8, 32), 256, 0, stream>>>(ffh16, W2T, fb2 + (size_t)l * D, ao, nullptr, F, D, 0);
        float* dstF = (l == NLAYER - 1) ? out : xb;
        bf16* dstB = (l == NLAYER - 1) ? nullptr : xb16;
        add_ln_kernel<<<S, 128, 0, stream>>>(xb, ao, lng + (size_t)(l * 3 + 2) * D, lnb + (size_t)(l * 3 + 2) * D, dstF, dstB);
    }
}

// Round 6
// 448.222 us; speedup vs baseline: 1.0304x; 1.0304x over previous
//
#include <hip/hip_runtime.h>
#include <hip/hip_bf16.h>
#include <math.h>

#define S 2048
#define D 512
#define H 8
#define DH 64
#define F 2048
#define NLAYER 2
#define QKVLD 1536   // qkv buffer row stride (3*D)

typedef __attribute__((ext_vector_type(8))) short bf16x8;
typedef __attribute__((ext_vector_type(4))) float f32x4;
typedef __hip_bfloat16 bf16;

typedef __attribute__((address_space(3))) unsigned int lds_u32;
typedef __attribute__((address_space(1))) const unsigned int glb_u32;

__device__ __forceinline__ void gld16(const void* g, void* l) {
    __builtin_amdgcn_global_load_lds((glb_u32*)g, (lds_u32*)l, 16, 0, 0);
}

// ---------------- positional encoding add (fp32 + bf16 mirror) ----------------
__global__ void pos_add_kernel(const float* __restrict__ x, float* __restrict__ outF,
                               bf16* __restrict__ outB) {
    int idx = blockIdx.x * blockDim.x + threadIdx.x;
    if (idx >= S * D) return;
    int s = idx / D;
    int j = idx % D;
    int jj = (j < D / 2) ? j : j - D / 2;
    float rate = expf(-(float)jj * (logf(10000.0f) / (float)(D / 2)));
    float ang = (float)s * rate;
    float pe = (j < D / 2) ? sinf(ang) : cosf(ang);
    float v = x[idx] + pe;
    outF[idx] = v;
    outB[idx] = __float2bfloat16(v);
}

// ---------------- fp32 -> bf16 convert ----------------
__global__ void cvt_kernel(const float* __restrict__ in, bf16* __restrict__ out, int n) {
    int idx = blockIdx.x * blockDim.x + threadIdx.x;
    if (idx < n) out[idx] = __float2bfloat16(in[idx]);
}

// ---------------- batched transpose + convert ----------------
__global__ __launch_bounds__(256)
void transpose_cvt_b(const float* __restrict__ in, bf16* __restrict__ out, int R, int C,
                     size_t inStride, size_t outL, size_t outM, int mpl)
{
    __shared__ float t[64][65];
    const int z = blockIdx.z;
    const float* src = in + (size_t)z * inStride;
    bf16* dst = out + (size_t)(z / mpl) * outL + (size_t)(z % mpl) * outM;
    const int rb = blockIdx.x * 64, cb = blockIdx.y * 64;
    for (int i = threadIdx.x; i < 4096; i += 256) {
        int r = i >> 6, c = i & 63;
        t[r][c] = src[(size_t)(rb + r) * C + cb + c];
    }
    __syncthreads();
    for (int i = threadIdx.x; i < 4096; i += 256) {
        int r = i >> 6, c = i & 63;
        dst[(size_t)(cb + r) * R + rb + c] = __float2bfloat16(t[c][r]);
    }
}

// ---------------- V transpose: Vt[d][s] = QKV[s][1024 + d] ----------------
__global__ __launch_bounds__(256)
void vt_kernel(const bf16* __restrict__ qkv, bf16* __restrict__ vt)
{
    __shared__ short t[64][72];
    const int sb = blockIdx.x * 64;   // seq tile
    const int db = blockIdx.y * 64;   // d tile (0..511 across heads)
    for (int i = threadIdx.x; i < 512; i += 256) {
        int r = i >> 3, c8 = (i & 7) * 8;
        *(bf16x8*)&t[r][c8] = *(const bf16x8*)(qkv + (size_t)(sb + r) * QKVLD + 2 * D + db + c8);
    }
    __syncthreads();
    for (int i = threadIdx.x; i < 512; i += 256) {
        int d = i >> 3, s8 = (i & 7) * 8;
        bf16x8 v;
#pragma unroll
        for (int j = 0; j < 8; ++j) v[j] = t[s8 + j][d];
        *(bf16x8*)(vt + (size_t)(db + d) * S + sb + s8) = v;
    }
}

// ---------------- bf16 MFMA GEMM: out = A[M,K] @ Bt[N,K]^T + bias ----------------
template<int BM, int BN>
__global__ __launch_bounds__(256)
void gemm_bf16(const bf16* __restrict__ A, const bf16* __restrict__ Bt,
               const float* __restrict__ bias, float* __restrict__ outF,
               bf16* __restrict__ outB, int K, int ldc, int relu)
{
    constexpr int MI = BM / 32, NJ = BN / 32;
    __shared__ char lds[(BM + BN) * 64];
    const int tid = threadIdx.x;
    const int w = tid >> 6, l = tid & 63;
    const int l15 = l & 15, l4 = l >> 4;
    const int bm = blockIdx.y * BM, bn = blockIdx.x * BN;
    const int wr = (w >> 1) * (BM / 2), wc = (w & 1) * (BN / 2);

    f32x4 acc[MI][NJ] = {};
    const int sp = l & 3;          // physical 16B slot within 64B row

    for (int k0 = 0; k0 < K; k0 += 32) {
#pragma unroll
        for (int i = 0; i < BM / 64; ++i) {
            int row = w * (BM / 4) + i * 16 + (l >> 2);
            int sl = (sp ^ ((row >> 1) & 3)) * 8;
            gld16(A + (size_t)(bm + row) * K + k0 + sl, lds + (w * (BM / 4) + i * 16) * 64);
        }
#pragma unroll
        for (int i = 0; i < BN / 64; ++i) {
            int row = w * (BN / 4) + i * 16 + (l >> 2);
            int sl = (sp ^ ((row >> 1) & 3)) * 8;
            gld16(Bt + (size_t)(bn + row) * K + k0 + sl, lds + BM * 64 + (w * (BN / 4) + i * 16) * 64);
        }
        __syncthreads();
        bf16x8 af[MI], bfr[NJ];
#pragma unroll
        for (int i = 0; i < MI; ++i) {
            int row = wr + i * 16 + l15;
            af[i] = *(const bf16x8*)(lds + row * 64 + ((l4 ^ ((row >> 1) & 3)) << 4));
        }
#pragma unroll
        for (int j = 0; j < NJ; ++j) {
            int row = wc + j * 16 + l15;
            bfr[j] = *(const bf16x8*)(lds + BM * 64 + row * 64 + ((l4 ^ ((row >> 1) & 3)) << 4));
        }
#pragma unroll
        for (int i = 0; i < MI; ++i)
#pragma unroll
            for (int j = 0; j < NJ; ++j)
                acc[i][j] = __builtin_amdgcn_mfma_f32_16x16x32_bf16(af[i], bfr[j], acc[i][j], 0, 0, 0);
        __syncthreads();
    }

#pragma unroll
    for (int i = 0; i < MI; ++i)
#pragma unroll
        for (int j = 0; j < NJ; ++j)
#pragma unroll
            for (int q = 0; q < 4; ++q) {
                int row = bm + wr + i * 16 + l4 * 4 + q;
                int col = bn + wc + j * 16 + l15;
                float v = acc[i][j][q] + bias[col];
                if (relu) v = fmaxf(v, 0.f);
                if (outF) outF[(size_t)row * ldc + col] = v;
                if (outB) outB[(size_t)row * ldc + col] = __float2bfloat16(v);
            }
}

// ---------------- split-key MFMA flash attention, 8-way split ----------
// Block = 8 waves (512 thr), one (head, q-tile of 16). Wave w handles 64-key
// chunks c ≡ w (mod 8). Swapped QK^T (mfma(K,Q)): lane l holds P for q=l&15.
// Q pre-scaled by 0.125*log2(e); softmax in log2 domain (exp2); defer-max.
// Merge: each wave stores its o-partial as bf16 OVER its own P tile (safe:
// only the owning wave ever reads its P tile), m/l in a 1KB strip; one
// barrier; 512 threads merge 8 partials. LDS total 17408 B.
// Grid: (H, S/16)  -> x = head (XCD locality on K/V), y = q-tile.
template<int CAUSAL>
__global__ __launch_bounds__(512, 6)
void attn_mfma5(const bf16* __restrict__ QKV, const bf16* __restrict__ Vt,
                bf16* __restrict__ O)
{
    // [0, 16384): per-wave P tiles (2048 each: 16 q x 64 keys bf16, XOR-swz),
    //             reused after the loop as bf16 o-partials [16 q][64 d].
    // [16384, 17408): m/l strip: wave w at +w*128, q at +q*8 (m, l floats).
    __shared__ char lds[17408];
    const int tid = threadIdx.x;
    const int w = tid >> 6, l = tid & 63;
    const int l15 = l & 15, l4 = l >> 4;
    const int h = blockIdx.x, qt = blockIdx.y;
    const int qbase = qt * 16;
    const int qr = qbase + l15;
    char* plds = lds + w * 2048;

    // load Q fragment, pre-scaled by 0.125 * log2(e)
    const float QSC = 0.1803368801f;
    bf16x8 aq[2];
#pragma unroll
    for (int s = 0; s < 2; ++s) {
        bf16x8 raw = *(const bf16x8*)(QKV + (size_t)(qbase + l15) * QKVLD + h * DH + s * 32 + l4 * 8);
#pragma unroll
        for (int j = 0; j < 8; ++j) {
            float f = __builtin_bit_cast(float, ((unsigned int)(unsigned short)raw[j]) << 16) * QSC;
            raw[j] = __builtin_bit_cast(short, __float2bfloat16(f));
        }
        aq[s] = raw;
    }

    f32x4 o[4] = {};              // o[dt]: q = l4*4+reg, d = dt*16+l15
    float mrun = -1e30f, lrun = 0.f;

    const int cdiag = qt >> 2;                    // causal diagonal 64-chunk
    const int cmax = CAUSAL ? cdiag : (S / 64 - 1);
    for (int c = w; c <= cmax; c += 8) {
        const int kbase = c * 64;

        // S^T tiles: rows=keys, cols=q
        f32x4 st[4];
#pragma unroll
        for (int t = 0; t < 4; ++t) {
            f32x4 sacc = {0.f, 0.f, 0.f, 0.f};
#pragma unroll
            for (int s = 0; s < 2; ++s) {
                bf16x8 kf = *(const bf16x8*)(QKV + (size_t)(kbase + t * 16 + l15) * QKVLD
                                             + D + h * DH + s * 32 + l4 * 8);
                sacc = __builtin_amdgcn_mfma_f32_16x16x32_bf16(kf, aq[s], sacc, 0, 0, 0);
            }
            st[t] = sacc;
        }

        // mask + per-lane max over the 16 held values (all for q = l15)
        float mx = -1e30f;
#pragma unroll
        for (int t = 0; t < 4; ++t)
#pragma unroll
            for (int r = 0; r < 4; ++r) {
                float v = st[t][r];
                if (CAUSAL && c == cdiag) {
                    int key = kbase + t * 16 + l4 * 4 + r;
                    if (key > qr) v = -1e30f;
                }
                st[t][r] = v;
                mx = fmaxf(mx, v);
            }
        mx = fmaxf(mx, __shfl_xor(mx, 16));
        mx = fmaxf(mx, __shfl_xor(mx, 32));

        // defer-max: only rescale when max grew past threshold (log2 units)
        if (__any(mx > mrun + 8.0f)) {
            float mnew = fmaxf(mrun, mx);
            float scl = exp2f(mrun - mnew);
            mrun = mnew;
            lrun *= scl;
#pragma unroll
            for (int j = 0; j < 4; ++j) {
                float sj = __shfl(scl, (l & 48) | (l4 * 4 + j));
#pragma unroll
                for (int dt = 0; dt < 4; ++dt) o[dt][j] *= sj;
            }
        }

        float ps = 0.f;
#pragma unroll
        for (int t = 0; t < 4; ++t) {
            float e0 = exp2f(st[t][0] - mrun);
            float e1 = exp2f(st[t][1] - mrun);
            float e2 = exp2f(st[t][2] - mrun);
            float e3 = exp2f(st[t][3] - mrun);
            ps += (e0 + e1) + (e2 + e3);
            unsigned int lo = (unsigned int)(unsigned short)__builtin_bit_cast(short, __float2bfloat16(e0))
                            | ((unsigned int)(unsigned short)__builtin_bit_cast(short, __float2bfloat16(e1)) << 16);
            unsigned int hi = (unsigned int)(unsigned short)__builtin_bit_cast(short, __float2bfloat16(e2))
                            | ((unsigned int)(unsigned short)__builtin_bit_cast(short, __float2bfloat16(e3)) << 16);
            uint2 pk; pk.x = lo; pk.y = hi;
            int byte = (l15 * 128 + t * 32 + l4 * 8) ^ ((l15 & 7) << 4);
            *(uint2*)(plds + byte) = pk;
        }
        ps += __shfl_xor(ps, 16);
        ps += __shfl_xor(ps, 32);
        lrun += ps;

        // PV: A-frag from plds (row=q=l15, k=key), B-frag from Vt (contiguous)
        bf16x8 pf[2];
#pragma unroll
        for (int s = 0; s < 2; ++s) {
            int byte = (l15 * 128 + s * 64 + l4 * 16) ^ ((l15 & 7) << 4);
            pf[s] = *(const bf16x8*)(plds + byte);
        }
#pragma unroll
        for (int dt = 0; dt < 4; ++dt) {
#pragma unroll
            for (int s = 0; s < 2; ++s) {
                bf16x8 vf = *(const bf16x8*)(Vt + (size_t)(h * DH + dt * 16 + l15) * S
                                             + kbase + s * 32 + l4 * 8);
                o[dt] = __builtin_amdgcn_mfma_f32_16x16x32_bf16(pf[s], vf, o[dt], 0, 0, 0);
            }
        }
    }

    // ---- store partials: o as bf16 over own P tile, m/l in strip ----
    // physical col-byte = (2*d) ^ (((q>>2)&3)<<5) within the 128B row of q.
#pragma unroll
    for (int dt = 0; dt < 4; ++dt)
#pragma unroll
        for (int j = 0; j < 4; ++j) {
            int q = l4 * 4 + j;
            int byte = q * 128 + (((dt * 32 + l15 * 2)) ^ ((l4 & 3) << 5));
            *(short*)(plds + byte) = __builtin_bit_cast(short, __float2bfloat16(o[dt][j]));
        }
    if (l < 16) {
        *(float*)(lds + 16384 + w * 128 + l * 8) = mrun;
        *(float*)(lds + 16384 + w * 128 + l * 8 + 4) = lrun;
    }
    __syncthreads();

    // ---- merge 8 partials: thread t -> q = t>>5, d0 = (t&31)*2 (log2 dom) ----
    const int q = tid >> 5, dp = tid & 31;
    float mt = -1e30f;
    float mv[8], lv[8];
#pragma unroll
    for (int ww = 0; ww < 8; ++ww) {
        mv[ww] = *(float*)(lds + 16384 + ww * 128 + q * 8);
        lv[ww] = *(float*)(lds + 16384 + ww * 128 + q * 8 + 4);
        mt = fmaxf(mt, mv[ww]);
    }
    float lt = 0.f, acc0 = 0.f, acc1 = 0.f;
    const int cb = q * 128 + ((dp * 4) ^ (((q >> 2) & 3) << 5));
#pragma unroll
    for (int ww = 0; ww < 8; ++ww) {
        float f = exp2f(mv[ww] - mt);
        lt += f * lv[ww];
        unsigned int pr = *(unsigned int*)(lds + ww * 2048 + cb);
        float o0 = __builtin_bit_cast(float, (pr & 0xffffu) << 16);
        float o1 = __builtin_bit_cast(float, pr & 0xffff0000u);
        acc0 += f * o0; acc1 += f * o1;
    }
    float inv = 1.f / lt;
    bf16* op = O + (size_t)(qbase + q) * D + h * DH + dp * 2;
    op[0] = __float2bfloat16(acc0 * inv);
    op[1] = __float2bfloat16(acc1 * inv);
}

// ---------------- residual add + layernorm (fp32, optional bf16 mirror) ----------------
__global__ __launch_bounds__(128)
void add_ln_kernel(const float* __restrict__ a, const float* __restrict__ b,
                   const float* __restrict__ g, const float* __restrict__ beta,
                   float* __restrict__ outF, bf16* __restrict__ outB)
{
    const int row = blockIdx.x;
    const int tid = threadIdx.x;
    float4 av = *(const float4*)&a[(size_t)row * D + tid * 4];
    float4 bv = *(const float4*)&b[(size_t)row * D + tid * 4];
    float4 s;
    s.x = av.x + bv.x; s.y = av.y + bv.y; s.z = av.z + bv.z; s.w = av.w + bv.w;
    float sum = s.x + s.y + s.z + s.w;
    float sq = s.x * s.x + s.y * s.y + s.z * s.z + s.w * s.w;
#pragma unroll
    for (int off = 32; off > 0; off >>= 1) {
        sum += __shfl_xor(sum, off);
        sq  += __shfl_xor(sq, off);
    }
    __shared__ float red[4];
    if ((tid & 63) == 0) { red[(tid >> 6) * 2] = sum; red[(tid >> 6) * 2 + 1] = sq; }
    __syncthreads();
    sum = red[0] + red[2];
    sq  = red[1] + red[3];
    float mu = sum / (float)D;
    float var = sq / (float)D - mu * mu;
    float rs = rsqrtf(var + 1e-6f);
    float4 gv = *(const float4*)&g[tid * 4];
    float4 bt = *(const float4*)&beta[tid * 4];
    float4 o;
    o.x = (s.x - mu) * rs * gv.x + bt.x;
    o.y = (s.y - mu) * rs * gv.y + bt.y;
    o.z = (s.z - mu) * rs * gv.z + bt.z;
    o.w = (s.w - mu) * rs * gv.w + bt.w;
    *(float4*)&outF[(size_t)row * D + tid * 4] = o;
    if (outB) {
        outB[(size_t)row * D + tid * 4 + 0] = __float2bfloat16(o.x);
        outB[(size_t)row * D + tid * 4 + 1] = __float2bfloat16(o.y);
        outB[(size_t)row * D + tid * 4 + 2] = __float2bfloat16(o.z);
        outB[(size_t)row * D + tid * 4 + 3] = __float2bfloat16(o.w);
    }
}

extern "C" void kernel_launch(void* const* d_in, const int* in_sizes, int n_in,
                              void* d_out, int out_size, void* d_ws, size_t ws_size,
                              hipStream_t stream)
{
    const float* x   = (const float*)d_in[0];
    const float* enc = (const float*)d_in[1];
    const float* a1w = (const float*)d_in[2];
    const float* a1b = (const float*)d_in[3];
    const float* a2w = (const float*)d_in[4];
    const float* a2b = (const float*)d_in[5];
    const float* fw1 = (const float*)d_in[6];
    const float* fb1 = (const float*)d_in[7];
    const float* fw2 = (const float*)d_in[8];
    const float* fb2 = (const float*)d_in[9];
    const float* lng = (const float*)d_in[10];
    const float* lnb = (const float*)d_in[11];
    float* out = (float*)d_out;

    char* wsb = (char*)d_ws;
    float* xb   = (float*)(wsb);                       // 4 MB
    float* ao   = (float*)(wsb + ((size_t)4 << 20));   // 4 MB
    bf16* xb16  = (bf16*)(wsb + ((size_t)8 << 20));    // 2 MB
    bf16* enc16 = (bf16*)(wsb + ((size_t)10 << 20));   // 2 MB
    bf16* att16 = (bf16*)(wsb + ((size_t)12 << 20));   // 2 MB
    bf16* qkv16 = (bf16*)(wsb + ((size_t)14 << 20));   // 6 MB [S][1536]
    bf16* vt16  = (bf16*)(wsb + ((size_t)20 << 20));   // 2 MB [512][S]
    bf16* ffh16 = qkv16;                               // 8 MB (overlaps vt16; disjoint lifetime)
    bf16* wts   = (bf16*)(wsb + ((size_t)22 << 20));   // 16 MB
    const size_t WCH = 1048576;
    const size_t DD = (size_t)D * D, DF = (size_t)D * F;

    // ---- weight prep (batched): transpose + bf16 ----
    transpose_cvt_b<<<dim3(8, 8, 8), 256, 0, stream>>>(a1w, wts,            D, D, DD, WCH, DD, 4);
    transpose_cvt_b<<<dim3(8, 8, 8), 256, 0, stream>>>(a2w, wts + 2 * WCH,  D, D, DD, WCH, DD, 4);
    transpose_cvt_b<<<dim3(8, 32, 2), 256, 0, stream>>>(fw1, wts + 4 * WCH, D, F, DF, WCH, 0, 1);
    transpose_cvt_b<<<dim3(32, 8, 2), 256, 0, stream>>>(fw2, wts + 6 * WCH, F, D, DF, WCH, 0, 1);
    cvt_kernel<<<(S * D + 255) / 256, 256, 0, stream>>>(enc, enc16, S * D);
    pos_add_kernel<<<(S * D + 255) / 256, 256, 0, stream>>>(x, xb, xb16);

    for (int l = 0; l < NLAYER; ++l) {
        const bf16* A1T = wts + (size_t)(0 + l) * WCH;
        const bf16* A2T = wts + (size_t)(2 + l) * WCH;
        const bf16* W1T = wts + (size_t)(4 + l) * WCH;
        const bf16* W2T = wts + (size_t)(6 + l) * WCH;
        const float* b1v = a1b + (size_t)l * 4 * D;
        const float* b2v = a2b + (size_t)l * 4 * D;

        // self-attention
        gemm_bf16<64, 64><<<dim3(24, 32), 256, 0, stream>>>(xb16, A1T, b1v, nullptr, qkv16, D, QKVLD, 0);
        vt_kernel<<<dim3(32, 8), 256, 0, stream>>>(qkv16, vt16);
        attn_mfma5<1><<<dim3(H, S / 16), 512, 0, stream>>>(qkv16, vt16, att16);
        gemm_bf16<64, 64><<<dim3(8, 32), 256, 0, stream>>>(att16, A1T + 3 * DD, b1v + 3 * D, ao, nullptr, D, D, 0);
        add_ln_kernel<<<S, 128, 0, stream>>>(xb, ao, lng + (size_t)(l * 3 + 0) * D, lnb + (size_t)(l * 3 + 0) * D, xb, xb16);

        // cross-attention
        gemm_bf16<64, 64><<<dim3(8, 32), 256, 0, stream>>>(xb16, A2T, b2v, nullptr, qkv16, D, QKVLD, 0);
        gemm_bf16<64, 64><<<dim3(16, 32), 256, 0, stream>>>(enc16, A2T + DD, b2v + D, nullptr, qkv16 + D, D, QKVLD, 0);
        vt_kernel<<<dim3(32, 8), 256, 0, stream>>>(qkv16, vt16);
        attn_mfma5<0><<<dim3(H, S / 16), 512, 0, stream>>>(qkv16, vt16, att16);
        gemm_bf16<64, 64><<<dim3(8, 32), 256, 0, stream>>>(att16, A2T + 3 * DD, b2v + 3 * D, ao, nullptr, D, D, 0);
        add_ln_kernel<<<S, 128, 0, stream>>>(xb, ao, lng + (size_t)(l * 3 + 1) * D, lnb + (size_t)(l * 3 + 1) * D, xb, xb16);

        // FFN
        gemm_bf16<128, 128><<<dim3(16, 16), 256, 0, stream>>>(xb16, W1T, fb1 + (size_t)l * F, nullptr, ffh16, D, F, 1);
        gemm_bf16<64, 64><<<dim3(8, 32), 256, 0, stream>>>(ffh16, W2T, fb2 + (size_t)l * D, ao, nullptr, F, D, 0);
        float* dstF = (l == NLAYER - 1) ? out : xb;
        bf16* dstB = (l == NLAYER - 1) ? nullptr : xb16;
        add_ln_kernel<<<S, 128, 0, stream>>>(xb, ao, lng + (size_t)(l * 3 + 2) * D, lnb + (size_t)(l * 3 + 2) * D, dstF, dstB);
    }
}

// Round 7
// 382.533 us; speedup vs baseline: 1.2073x; 1.1717x over previous
//
#include <hip/hip_runtime.h>
#include <hip/hip_bf16.h>
#include <math.h>

#define S 2048
#define D 512
#define H 8
#define DH 64
#define F 2048
#define NLAYER 2
#define QKVLD 1536   // qkv buffer row stride (3*D)

typedef __attribute__((ext_vector_type(8))) short bf16x8;
typedef __attribute__((ext_vector_type(4))) float f32x4;
typedef __hip_bfloat16 bf16;

typedef __attribute__((address_space(3))) unsigned int lds_u32;
typedef __attribute__((address_space(1))) const unsigned int glb_u32;

__device__ __forceinline__ void gld16(const void* g, void* l) {
    __builtin_amdgcn_global_load_lds((glb_u32*)g, (lds_u32*)l, 16, 0, 0);
}

// ---------------- positional encoding add (fp32 + bf16 mirror) ----------------
__global__ void pos_add_kernel(const float* __restrict__ x, float* __restrict__ outF,
                               bf16* __restrict__ outB) {
    int idx = blockIdx.x * blockDim.x + threadIdx.x;
    if (idx >= S * D) return;
    int s = idx / D;
    int j = idx % D;
    int jj = (j < D / 2) ? j : j - D / 2;
    float rate = expf(-(float)jj * (logf(10000.0f) / (float)(D / 2)));
    float ang = (float)s * rate;
    float pe = (j < D / 2) ? sinf(ang) : cosf(ang);
    float v = x[idx] + pe;
    outF[idx] = v;
    outB[idx] = __float2bfloat16(v);
}

// ---------------- fp32 -> bf16 convert ----------------
__global__ void cvt_kernel(const float* __restrict__ in, bf16* __restrict__ out, int n) {
    int idx = blockIdx.x * blockDim.x + threadIdx.x;
    if (idx < n) out[idx] = __float2bfloat16(in[idx]);
}

// ---------------- batched transpose + convert ----------------
__global__ __launch_bounds__(256)
void transpose_cvt_b(const float* __restrict__ in, bf16* __restrict__ out, int R, int C,
                     size_t inStride, size_t outL, size_t outM, int mpl)
{
    __shared__ float t[64][65];
    const int z = blockIdx.z;
    const float* src = in + (size_t)z * inStride;
    bf16* dst = out + (size_t)(z / mpl) * outL + (size_t)(z % mpl) * outM;
    const int rb = blockIdx.x * 64, cb = blockIdx.y * 64;
    for (int i = threadIdx.x; i < 4096; i += 256) {
        int r = i >> 6, c = i & 63;
        t[r][c] = src[(size_t)(rb + r) * C + cb + c];
    }
    __syncthreads();
    for (int i = threadIdx.x; i < 4096; i += 256) {
        int r = i >> 6, c = i & 63;
        dst[(size_t)(cb + r) * R + rb + c] = __float2bfloat16(t[c][r]);
    }
}

// ---------------- K head-pack + V transpose ----------------
// kh[h][s][64] = QKV[s][512 + h*64 + d];  vt[h*64+d][s] = QKV[s][1024 + h*64 + d]
__global__ __launch_bounds__(256)
void kvt_kernel(const bf16* __restrict__ qkv, bf16* __restrict__ kh, bf16* __restrict__ vt)
{
    __shared__ short t[64][72];
    const int sb = blockIdx.x * 64;   // seq tile
    const int db = blockIdx.y * 64;   // = head * 64
    for (int i = threadIdx.x; i < 512; i += 256) {
        int r = i >> 3, c8 = (i & 7) * 8;
        *(bf16x8*)(kh + ((size_t)blockIdx.y * S + sb + r) * 64 + c8) =
            *(const bf16x8*)(qkv + (size_t)(sb + r) * QKVLD + D + db + c8);
    }
    for (int i = threadIdx.x; i < 512; i += 256) {
        int r = i >> 3, c8 = (i & 7) * 8;
        *(bf16x8*)&t[r][c8] = *(const bf16x8*)(qkv + (size_t)(sb + r) * QKVLD + 2 * D + db + c8);
    }
    __syncthreads();
    for (int i = threadIdx.x; i < 512; i += 256) {
        int d = i >> 3, s8 = (i & 7) * 8;
        bf16x8 v;
#pragma unroll
        for (int j = 0; j < 8; ++j) v[j] = t[s8 + j][d];
        *(bf16x8*)(vt + (size_t)(db + d) * S + sb + s8) = v;
    }
}

// ---------------- bf16 MFMA GEMM: out = A[M,K] @ Bt[N,K]^T + bias ----------------
template<int BM, int BN>
__global__ __launch_bounds__(256)
void gemm_bf16(const bf16* __restrict__ A, const bf16* __restrict__ Bt,
               const float* __restrict__ bias, float* __restrict__ outF,
               bf16* __restrict__ outB, int K, int ldc, int relu)
{
    constexpr int MI = BM / 32, NJ = BN / 32;
    __shared__ char lds[(BM + BN) * 64];
    const int tid = threadIdx.x;
    const int w = tid >> 6, l = tid & 63;
    const int l15 = l & 15, l4 = l >> 4;
    const int bm = blockIdx.y * BM, bn = blockIdx.x * BN;
    const int wr = (w >> 1) * (BM / 2), wc = (w & 1) * (BN / 2);

    f32x4 acc[MI][NJ] = {};
    const int sp = l & 3;          // physical 16B slot within 64B row

    for (int k0 = 0; k0 < K; k0 += 32) {
#pragma unroll
        for (int i = 0; i < BM / 64; ++i) {
            int row = w * (BM / 4) + i * 16 + (l >> 2);
            int sl = (sp ^ ((row >> 1) & 3)) * 8;
            gld16(A + (size_t)(bm + row) * K + k0 + sl, lds + (w * (BM / 4) + i * 16) * 64);
        }
#pragma unroll
        for (int i = 0; i < BN / 64; ++i) {
            int row = w * (BN / 4) + i * 16 + (l >> 2);
            int sl = (sp ^ ((row >> 1) & 3)) * 8;
            gld16(Bt + (size_t)(bn + row) * K + k0 + sl, lds + BM * 64 + (w * (BN / 4) + i * 16) * 64);
        }
        __syncthreads();
        bf16x8 af[MI], bfr[NJ];
#pragma unroll
        for (int i = 0; i < MI; ++i) {
            int row = wr + i * 16 + l15;
            af[i] = *(const bf16x8*)(lds + row * 64 + ((l4 ^ ((row >> 1) & 3)) << 4));
        }
#pragma unroll
        for (int j = 0; j < NJ; ++j) {
            int row = wc + j * 16 + l15;
            bfr[j] = *(const bf16x8*)(lds + BM * 64 + row * 64 + ((l4 ^ ((row >> 1) & 3)) << 4));
        }
#pragma unroll
        for (int i = 0; i < MI; ++i)
#pragma unroll
            for (int j = 0; j < NJ; ++j)
                acc[i][j] = __builtin_amdgcn_mfma_f32_16x16x32_bf16(af[i], bfr[j], acc[i][j], 0, 0, 0);
        __syncthreads();
    }

#pragma unroll
    for (int i = 0; i < MI; ++i)
#pragma unroll
        for (int j = 0; j < NJ; ++j)
#pragma unroll
            for (int q = 0; q < 4; ++q) {
                int row = bm + wr + i * 16 + l4 * 4 + q;
                int col = bn + wc + j * 16 + l15;
                float v = acc[i][j][q] + bias[col];
                if (relu) v = fmaxf(v, 0.f);
                if (outF) outF[(size_t)row * ldc + col] = v;
                if (outB) outB[(size_t)row * ldc + col] = __float2bfloat16(v);
            }
}

// ---------------- LDS-staged MFMA flash attention ----------------
// Block = 4 waves (256 thr) = one (head, 64-q-row tile); wave w owns q-rows
// qb*64 + w*16 .. +15 end-to-end (no merge). Each 64-key chunk's K (8KB,
// head-packed Kh) and V (8KB, d-major Vt) staged ONCE into LDS via bulk
// global_load_lds (dense 16B/lane), double-buffered, one barrier/chunk.
// XOR swizzle (rule 21): inverse-swizzled source slot + swizzled ds_read.
// Swapped QK^T (mfma(K,Q)); softmax log2-domain, Q pre-scaled; defer-max.
// Grid (H, S/64): same-head blocks land on one XCD (K/V L2-resident).
template<int CAUSAL>
__global__ __launch_bounds__(256)
void attn_mfma6(const bf16* __restrict__ QKV, const bf16* __restrict__ Kh,
                const bf16* __restrict__ Vt, bf16* __restrict__ O)
{
    // [0,8192) Kbuf0 | [8192,16384) Vbuf0 | [16384,24576) Kbuf1 |
    // [24576,32768) Vbuf1 | [32768,40960) P tiles (2KB/wave)
    __shared__ char lds[40960];
    const int tid = threadIdx.x;
    const int w = tid >> 6, l = tid & 63;
    const int l15 = l & 15, l4 = l >> 4;
    const int h = blockIdx.x, qb = blockIdx.y;
    const int qw = qb * 64 + w * 16;
    const int qr = qw + l15;
    char* plds = lds + 32768 + w * 2048;

    // Q fragment, pre-scaled by 0.125 * log2(e)
    const float QSC = 0.1803368801f;
    bf16x8 aq[2];
#pragma unroll
    for (int s = 0; s < 2; ++s) {
        bf16x8 raw = *(const bf16x8*)(QKV + (size_t)(qw + l15) * QKVLD + h * DH + s * 32 + l4 * 8);
#pragma unroll
        for (int j = 0; j < 8; ++j) {
            float f = __builtin_bit_cast(float, ((unsigned int)(unsigned short)raw[j]) << 16) * QSC;
            raw[j] = __builtin_bit_cast(short, __float2bfloat16(f));
        }
        aq[s] = raw;
    }

    f32x4 o[4] = {};              // o[dt]: q = l4*4+reg, d = dt*16+l15
    float mrun = -1e30f, lrun = 0.f;
    const int cmax = CAUSAL ? qb : (S / 64 - 1);

    // stage chunk c into buffer b: linear slot n holds global slot (n&7)^(row&7)
#define STAGE(c, b)                                                                 \
    {                                                                               \
        const int kb2 = (c) * 64;                                                   \
        _Pragma("unroll")                                                           \
        for (int i = 0; i < 2; ++i) {                                               \
            int n = w * 128 + i * 64 + l;                                           \
            int row = n >> 3;                                                       \
            int sl = (n & 7) ^ (row & 7);                                           \
            gld16(Kh + ((size_t)h * S + kb2 + row) * 64 + sl * 8,                   \
                  lds + (b) * 16384 + w * 2048 + i * 1024);                         \
            gld16(Vt + ((size_t)(h * 64 + row)) * S + kb2 + sl * 8,                 \
                  lds + (b) * 16384 + 8192 + w * 2048 + i * 1024);                  \
        }                                                                           \
    }

    STAGE(0, 0);
    __syncthreads();

    int cur = 0;
    for (int c = 0; c <= cmax; ++c) {
        if (c < cmax) STAGE(c + 1, cur ^ 1);
        const char* kb = lds + cur * 16384;
        const char* vb = kb + 8192;
        const int kbase = c * 64;

        // S^T tiles: rows=keys, cols=q (ds_read_b128, swizzled)
        f32x4 st[4];
#pragma unroll
        for (int t = 0; t < 4; ++t) {
            f32x4 sacc = {0.f, 0.f, 0.f, 0.f};
#pragma unroll
            for (int s = 0; s < 2; ++s) {
                bf16x8 kf = *(const bf16x8*)(kb + (t * 16 + l15) * 128
                                             + (((s * 4 + l4) ^ (l15 & 7)) << 4));
                sacc = __builtin_amdgcn_mfma_f32_16x16x32_bf16(kf, aq[s], sacc, 0, 0, 0);
            }
            st[t] = sacc;
        }

        // mask + per-lane max (lane holds 16 values for q = l15)
        float mx = -1e30f;
#pragma unroll
        for (int t = 0; t < 4; ++t)
#pragma unroll
            for (int r = 0; r < 4; ++r) {
                float v = st[t][r];
                if (CAUSAL && c == cmax) {
                    int key = kbase + t * 16 + l4 * 4 + r;
                    if (key > qr) v = -1e30f;
                }
                st[t][r] = v;
                mx = fmaxf(mx, v);
            }
        mx = fmaxf(mx, __shfl_xor(mx, 16));
        mx = fmaxf(mx, __shfl_xor(mx, 32));

        // defer-max rescale (log2 units)
        if (__any(mx > mrun + 8.0f)) {
            float mnew = fmaxf(mrun, mx);
            float scl = exp2f(mrun - mnew);
            mrun = mnew;
            lrun *= scl;
#pragma unroll
            for (int j = 0; j < 4; ++j) {
                float sj = __shfl(scl, (l & 48) | (l4 * 4 + j));
#pragma unroll
                for (int dt = 0; dt < 4; ++dt) o[dt][j] *= sj;
            }
        }

        float ps = 0.f;
#pragma unroll
        for (int t = 0; t < 4; ++t) {
            float e0 = exp2f(st[t][0] - mrun);
            float e1 = exp2f(st[t][1] - mrun);
            float e2 = exp2f(st[t][2] - mrun);
            float e3 = exp2f(st[t][3] - mrun);
            ps += (e0 + e1) + (e2 + e3);
            unsigned int lo = (unsigned int)(unsigned short)__builtin_bit_cast(short, __float2bfloat16(e0))
                            | ((unsigned int)(unsigned short)__builtin_bit_cast(short, __float2bfloat16(e1)) << 16);
            unsigned int hi = (unsigned int)(unsigned short)__builtin_bit_cast(short, __float2bfloat16(e2))
                            | ((unsigned int)(unsigned short)__builtin_bit_cast(short, __float2bfloat16(e3)) << 16);
            uint2 pk; pk.x = lo; pk.y = hi;
            int byte = (l15 * 128 + t * 32 + l4 * 8) ^ ((l15 & 7) << 4);
            *(uint2*)(plds + byte) = pk;
        }
        ps += __shfl_xor(ps, 16);
        ps += __shfl_xor(ps, 32);
        lrun += ps;

        // PV: A-frag from plds, B-frag from staged Vt (swizzled ds_read)
        bf16x8 pf[2];
#pragma unroll
        for (int s = 0; s < 2; ++s) {
            int byte = (l15 * 128 + s * 64 + l4 * 16) ^ ((l15 & 7) << 4);
            pf[s] = *(const bf16x8*)(plds + byte);
        }
#pragma unroll
        for (int dt = 0; dt < 4; ++dt)
#pragma unroll
            for (int s = 0; s < 2; ++s) {
                bf16x8 vf = *(const bf16x8*)(vb + (dt * 16 + l15) * 128
                                             + (((s * 4 + l4) ^ (l15 & 7)) << 4));
                o[dt] = __builtin_amdgcn_mfma_f32_16x16x32_bf16(pf[s], vf, o[dt], 0, 0, 0);
            }

        __syncthreads();
        cur ^= 1;
    }
#undef STAGE

    float linv[4];
#pragma unroll
    for (int j = 0; j < 4; ++j)
        linv[j] = 1.f / __shfl(lrun, (l & 48) | (l4 * 4 + j));
#pragma unroll
    for (int dt = 0; dt < 4; ++dt)
#pragma unroll
        for (int j = 0; j < 4; ++j)
            O[(size_t)(qw + l4 * 4 + j) * D + h * DH + dt * 16 + l15] =
                __float2bfloat16(o[dt][j] * linv[j]);
}

// ---------------- residual add + layernorm (fp32, optional bf16 mirror) ----------------
__global__ __launch_bounds__(128)
void add_ln_kernel(const float* __restrict__ a, const float* __restrict__ b,
                   const float* __restrict__ g, const float* __restrict__ beta,
                   float* __restrict__ outF, bf16* __restrict__ outB)
{
    const int row = blockIdx.x;
    const int tid = threadIdx.x;
    float4 av = *(const float4*)&a[(size_t)row * D + tid * 4];
    float4 bv = *(const float4*)&b[(size_t)row * D + tid * 4];
    float4 s;
    s.x = av.x + bv.x; s.y = av.y + bv.y; s.z = av.z + bv.z; s.w = av.w + bv.w;
    float sum = s.x + s.y + s.z + s.w;
    float sq = s.x * s.x + s.y * s.y + s.z * s.z + s.w * s.w;
#pragma unroll
    for (int off = 32; off > 0; off >>= 1) {
        sum += __shfl_xor(sum, off);
        sq  += __shfl_xor(sq, off);
    }
    __shared__ float red[4];
    if ((tid & 63) == 0) { red[(tid >> 6) * 2] = sum; red[(tid >> 6) * 2 + 1] = sq; }
    __syncthreads();
    sum = red[0] + red[2];
    sq  = red[1] + red[3];
    float mu = sum / (float)D;
    float var = sq / (float)D - mu * mu;
    float rs = rsqrtf(var + 1e-6f);
    float4 gv = *(const float4*)&g[tid * 4];
    float4 bt = *(const float4*)&beta[tid * 4];
    float4 o;
    o.x = (s.x - mu) * rs * gv.x + bt.x;
    o.y = (s.y - mu) * rs * gv.y + bt.y;
    o.z = (s.z - mu) * rs * gv.z + bt.z;
    o.w = (s.w - mu) * rs * gv.w + bt.w;
    *(float4*)&outF[(size_t)row * D + tid * 4] = o;
    if (outB) {
        outB[(size_t)row * D + tid * 4 + 0] = __float2bfloat16(o.x);
        outB[(size_t)row * D + tid * 4 + 1] = __float2bfloat16(o.y);
        outB[(size_t)row * D + tid * 4 + 2] = __float2bfloat16(o.z);
        outB[(size_t)row * D + tid * 4 + 3] = __float2bfloat16(o.w);
    }
}

extern "C" void kernel_launch(void* const* d_in, const int* in_sizes, int n_in,
                              void* d_out, int out_size, void* d_ws, size_t ws_size,
                              hipStream_t stream)
{
    const float* x   = (const float*)d_in[0];
    const float* enc = (const float*)d_in[1];
    const float* a1w = (const float*)d_in[2];
    const float* a1b = (const float*)d_in[3];
    const float* a2w = (const float*)d_in[4];
    const float* a2b = (const float*)d_in[5];
    const float* fw1 = (const float*)d_in[6];
    const float* fb1 = (const float*)d_in[7];
    const float* fw2 = (const float*)d_in[8];
    const float* fb2 = (const float*)d_in[9];
    const float* lng = (const float*)d_in[10];
    const float* lnb = (const float*)d_in[11];
    float* out = (float*)d_out;

    char* wsb = (char*)d_ws;
    float* xb   = (float*)(wsb);                       // 4 MB
    float* ao   = (float*)(wsb + ((size_t)4 << 20));   // 4 MB
    bf16* xb16  = (bf16*)(wsb + ((size_t)8 << 20));    // 2 MB
    bf16* enc16 = (bf16*)(wsb + ((size_t)10 << 20));   // 2 MB
    bf16* att16 = (bf16*)(wsb + ((size_t)12 << 20));   // 2 MB
    bf16* qkv16 = (bf16*)(wsb + ((size_t)14 << 20));   // 6 MB [S][1536]
    bf16* vt16  = (bf16*)(wsb + ((size_t)20 << 20));   // 2 MB [512][S]
    bf16* ffh16 = qkv16;                               // 8 MB (overlaps vt16; disjoint lifetime)
    bf16* wts   = (bf16*)(wsb + ((size_t)22 << 20));   // 16 MB
    bf16* kh16  = (bf16*)(wsb + ((size_t)38 << 20));   // 2 MB [H][S][64]
    const size_t WCH = 1048576;
    const size_t DD = (size_t)D * D, DF = (size_t)D * F;

    // ---- weight prep (batched): transpose + bf16 ----
    transpose_cvt_b<<<dim3(8, 8, 8), 256, 0, stream>>>(a1w, wts,            D, D, DD, WCH, DD, 4);
    transpose_cvt_b<<<dim3(8, 8, 8), 256, 0, stream>>>(a2w, wts + 2 * WCH,  D, D, DD, WCH, DD, 4);
    transpose_cvt_b<<<dim3(8, 32, 2), 256, 0, stream>>>(fw1, wts + 4 * WCH, D, F, DF, WCH, 0, 1);
    transpose_cvt_b<<<dim3(32, 8, 2), 256, 0, stream>>>(fw2, wts + 6 * WCH, F, D, DF, WCH, 0, 1);
    cvt_kernel<<<(S * D + 255) / 256, 256, 0, stream>>>(enc, enc16, S * D);
    pos_add_kernel<<<(S * D + 255) / 256, 256, 0, stream>>>(x, xb, xb16);

    for (int l = 0; l < NLAYER; ++l) {
        const bf16* A1T = wts + (size_t)(0 + l) * WCH;
        const bf16* A2T = wts + (size_t)(2 + l) * WCH;
        const bf16* W1T = wts + (size_t)(4 + l) * WCH;
        const bf16* W2T = wts + (size_t)(6 + l) * WCH;
        const float* b1v = a1b + (size_t)l * 4 * D;
        const float* b2v = a2b + (size_t)l * 4 * D;

        // self-attention
        gemm_bf16<64, 64><<<dim3(24, 32), 256, 0, stream>>>(xb16, A1T, b1v, nullptr, qkv16, D, QKVLD, 0);
        kvt_kernel<<<dim3(32, 8), 256, 0, stream>>>(qkv16, kh16, vt16);
        attn_mfma6<1><<<dim3(H, S / 64), 256, 0, stream>>>(qkv16, kh16, vt16, att16);
        gemm_bf16<64, 64><<<dim3(8, 32), 256, 0, stream>>>(att16, A1T + 3 * DD, b1v + 3 * D, ao, nullptr, D, D, 0);
        add_ln_kernel<<<S, 128, 0, stream>>>(xb, ao, lng + (size_t)(l * 3 + 0) * D, lnb + (size_t)(l * 3 + 0) * D, xb, xb16);

        // cross-attention
        gemm_bf16<64, 64><<<dim3(8, 32), 256, 0, stream>>>(xb16, A2T, b2v, nullptr, qkv16, D, QKVLD, 0);
        gemm_bf16<64, 64><<<dim3(16, 32), 256, 0, stream>>>(enc16, A2T + DD, b2v + D, nullptr, qkv16 + D, D, QKVLD, 0);
        kvt_kernel<<<dim3(32, 8), 256, 0, stream>>>(qkv16, kh16, vt16);
        attn_mfma6<0><<<dim3(H, S / 64), 256, 0, stream>>>(qkv16, kh16, vt16, att16);
        gemm_bf16<64, 64><<<dim3(8, 32), 256, 0, stream>>>(att16, A2T + 3 * DD, b2v + 3 * D, ao, nullptr, D, D, 0);
        add_ln_kernel<<<S, 128, 0, stream>>>(xb, ao, lng + (size_t)(l * 3 + 1) * D, lnb + (size_t)(l * 3 + 1) * D, xb, xb16);

        // FFN
        gemm_bf16<128, 128><<<dim3(16, 16), 256, 0, stream>>>(xb16, W1T, fb1 + (size_t)l * F, nullptr, ffh16, D, F, 1);
        gemm_bf16<64, 64><<<dim3(8, 32), 256, 0, stream>>>(ffh16, W2T, fb2 + (size_t)l * D, ao, nullptr, F, D, 0);
        float* dstF = (l == NLAYER - 1) ? out : xb;
        bf16* dstB = (l == NLAYER - 1) ? nullptr : xb16;
        add_ln_kernel<<<S, 128, 0, stream>>>(xb, ao, lng + (size_t)(l * 3 + 2) * D, lnb + (size_t)(l * 3 + 2) * D, dstF, dstB);
    }
}

// Round 8
// 357.145 us; speedup vs baseline: 1.2932x; 1.0711x over previous
//
#include <hip/hip_runtime.h>
#include <hip/hip_bf16.h>
#include <math.h>

#define S 2048
#define D 512
#define H 8
#define DH 64
#define F 2048
#define NLAYER 2
#define QKVLD 1536   // qkv buffer row stride (3*D)

typedef __attribute__((ext_vector_type(8))) short bf16x8;
typedef __attribute__((ext_vector_type(4))) float f32x4;
typedef __hip_bfloat16 bf16;

typedef __attribute__((address_space(3))) unsigned int lds_u32;
typedef __attribute__((address_space(1))) const unsigned int glb_u32;

__device__ __forceinline__ void gld16(const void* g, void* l) {
    __builtin_amdgcn_global_load_lds((glb_u32*)g, (lds_u32*)l, 16, 0, 0);
}

// ---------------- positional encoding add (fp32 + bf16 mirror) ----------------
__global__ void pos_add_kernel(const float* __restrict__ x, float* __restrict__ outF,
                               bf16* __restrict__ outB) {
    int idx = blockIdx.x * blockDim.x + threadIdx.x;
    if (idx >= S * D) return;
    int s = idx / D;
    int j = idx % D;
    int jj = (j < D / 2) ? j : j - D / 2;
    float rate = expf(-(float)jj * (logf(10000.0f) / (float)(D / 2)));
    float ang = (float)s * rate;
    float pe = (j < D / 2) ? sinf(ang) : cosf(ang);
    float v = x[idx] + pe;
    outF[idx] = v;
    outB[idx] = __float2bfloat16(v);
}

// ---------------- fp32 -> bf16 convert ----------------
__global__ void cvt_kernel(const float* __restrict__ in, bf16* __restrict__ out, int n) {
    int idx = blockIdx.x * blockDim.x + threadIdx.x;
    if (idx < n) out[idx] = __float2bfloat16(in[idx]);
}

// ---------------- batched transpose + convert ----------------
__global__ __launch_bounds__(256)
void transpose_cvt_b(const float* __restrict__ in, bf16* __restrict__ out, int R, int C,
                     size_t inStride, size_t outL, size_t outM, int mpl)
{
    __shared__ float t[64][65];
    const int z = blockIdx.z;
    const float* src = in + (size_t)z * inStride;
    bf16* dst = out + (size_t)(z / mpl) * outL + (size_t)(z % mpl) * outM;
    const int rb = blockIdx.x * 64, cb = blockIdx.y * 64;
    for (int i = threadIdx.x; i < 4096; i += 256) {
        int r = i >> 6, c = i & 63;
        t[r][c] = src[(size_t)(rb + r) * C + cb + c];
    }
    __syncthreads();
    for (int i = threadIdx.x; i < 4096; i += 256) {
        int r = i >> 6, c = i & 63;
        dst[(size_t)(cb + r) * R + rb + c] = __float2bfloat16(t[c][r]);
    }
}

// ---------------- K head-pack + V transpose ----------------
// kh[h][s][64] = QKV[s][512 + h*64 + d];  vt[h*64+d][s] = QKV[s][1024 + h*64 + d]
__global__ __launch_bounds__(256)
void kvt_kernel(const bf16* __restrict__ qkv, bf16* __restrict__ kh, bf16* __restrict__ vt)
{
    __shared__ short t[64][72];
    const int sb = blockIdx.x * 64;   // seq tile
    const int db = blockIdx.y * 64;   // = head * 64
    for (int i = threadIdx.x; i < 512; i += 256) {
        int r = i >> 3, c8 = (i & 7) * 8;
        *(bf16x8*)(kh + ((size_t)blockIdx.y * S + sb + r) * 64 + c8) =
            *(const bf16x8*)(qkv + (size_t)(sb + r) * QKVLD + D + db + c8);
    }
    for (int i = threadIdx.x; i < 512; i += 256) {
        int r = i >> 3, c8 = (i & 7) * 8;
        *(bf16x8*)&t[r][c8] = *(const bf16x8*)(qkv + (size_t)(sb + r) * QKVLD + 2 * D + db + c8);
    }
    __syncthreads();
    for (int i = threadIdx.x; i < 512; i += 256) {
        int d = i >> 3, s8 = (i & 7) * 8;
        bf16x8 v;
#pragma unroll
        for (int j = 0; j < 8; ++j) v[j] = t[s8 + j][d];
        *(bf16x8*)(vt + (size_t)(db + d) * S + sb + s8) = v;
    }
}

// ---------------- bf16 MFMA GEMM, 2-phase prefetch K-loop ----------------
// out = A[M,K] @ Bt[N,K]^T + bias. Double-buffered LDS; STAGE(k+1) issued
// BEFORE compute(k); single barrier (implicit vmcnt drain) per K-step.
template<int BM, int BN>
__global__ __launch_bounds__(256)
void gemm_bf16(const bf16* __restrict__ A, const bf16* __restrict__ Bt,
               const float* __restrict__ bias, float* __restrict__ outF,
               bf16* __restrict__ outB, int K, int ldc, int relu)
{
    constexpr int MI = BM / 32, NJ = BN / 32;
    constexpr int HALF = (BM + BN) * 64;
    __shared__ char lds[2 * HALF];
    const int tid = threadIdx.x;
    const int w = tid >> 6, l = tid & 63;
    const int l15 = l & 15, l4 = l >> 4;
    const int bm = blockIdx.y * BM, bn = blockIdx.x * BN;
    const int wr = (w >> 1) * (BM / 2), wc = (w & 1) * (BN / 2);

    f32x4 acc[MI][NJ] = {};
    const int sp = l & 3;          // physical 16B slot within 64B row

#define GSTAGE(k0, b)                                                         \
    {                                                                         \
        _Pragma("unroll")                                                     \
        for (int i = 0; i < BM / 64; ++i) {                                   \
            int row = w * (BM / 4) + i * 16 + (l >> 2);                       \
            int sl = (sp ^ ((row >> 1) & 3)) * 8;                             \
            gld16(A + (size_t)(bm + row) * K + (k0) + sl,                     \
                  lds + (b) * HALF + (w * (BM / 4) + i * 16) * 64);           \
        }                                                                     \
        _Pragma("unroll")                                                     \
        for (int i = 0; i < BN / 64; ++i) {                                   \
            int row = w * (BN / 4) + i * 16 + (l >> 2);                       \
            int sl = (sp ^ ((row >> 1) & 3)) * 8;                             \
            gld16(Bt + (size_t)(bn + row) * K + (k0) + sl,                    \
                  lds + (b) * HALF + BM * 64 + (w * (BN / 4) + i * 16) * 64); \
        }                                                                     \
    }

    GSTAGE(0, 0);
    __syncthreads();
    int cur = 0;
    for (int k0 = 0; k0 < K; k0 += 32) {
        if (k0 + 32 < K) GSTAGE(k0 + 32, cur ^ 1);
        const char* base = lds + cur * HALF;
        bf16x8 af[MI], bfr[NJ];
#pragma unroll
        for (int i = 0; i < MI; ++i) {
            int row = wr + i * 16 + l15;
            af[i] = *(const bf16x8*)(base + row * 64 + ((l4 ^ ((row >> 1) & 3)) << 4));
        }
#pragma unroll
        for (int j = 0; j < NJ; ++j) {
            int row = wc + j * 16 + l15;
            bfr[j] = *(const bf16x8*)(base + BM * 64 + row * 64 + ((l4 ^ ((row >> 1) & 3)) << 4));
        }
#pragma unroll
        for (int i = 0; i < MI; ++i)
#pragma unroll
            for (int j = 0; j < NJ; ++j)
                acc[i][j] = __builtin_amdgcn_mfma_f32_16x16x32_bf16(af[i], bfr[j], acc[i][j], 0, 0, 0);
        __syncthreads();
        cur ^= 1;
    }
#undef GSTAGE

#pragma unroll
    for (int i = 0; i < MI; ++i)
#pragma unroll
        for (int j = 0; j < NJ; ++j)
#pragma unroll
            for (int q = 0; q < 4; ++q) {
                int row = bm + wr + i * 16 + l4 * 4 + q;
                int col = bn + wc + j * 16 + l15;
                float v = acc[i][j][q] + bias[col];
                if (relu) v = fmaxf(v, 0.f);
                if (outF) outF[(size_t)row * ldc + col] = v;
                if (outB) outB[(size_t)row * ldc + col] = __float2bfloat16(v);
            }
}

// ---------------- LDS-staged MFMA flash attention ----------------
// Block = 4 waves (256 thr) = one (head, 64-q-row tile); wave w owns q-rows
// qb*64 + w*16 .. +15 end-to-end (no merge). Each 64-key chunk's K (8KB,
// head-packed Kh) and V (8KB, d-major Vt) staged ONCE into LDS via bulk
// global_load_lds (dense 16B/lane), double-buffered, one barrier/chunk.
// XOR swizzle (rule 21): inverse-swizzled source slot + swizzled ds_read.
// Swapped QK^T (mfma(K,Q)); softmax log2-domain, Q pre-scaled; defer-max.
// Grid (H, S/64): same-head blocks land on one XCD (K/V L2-resident).
template<int CAUSAL>
__global__ __launch_bounds__(256)
void attn_mfma6(const bf16* __restrict__ QKV, const bf16* __restrict__ Kh,
                const bf16* __restrict__ Vt, bf16* __restrict__ O)
{
    // [0,8192) Kbuf0 | [8192,16384) Vbuf0 | [16384,24576) Kbuf1 |
    // [24576,32768) Vbuf1 | [32768,40960) P tiles (2KB/wave)
    __shared__ char lds[40960];
    const int tid = threadIdx.x;
    const int w = tid >> 6, l = tid & 63;
    const int l15 = l & 15, l4 = l >> 4;
    const int h = blockIdx.x, qb = blockIdx.y;
    const int qw = qb * 64 + w * 16;
    const int qr = qw + l15;
    char* plds = lds + 32768 + w * 2048;

    // Q fragment, pre-scaled by 0.125 * log2(e)
    const float QSC = 0.1803368801f;
    bf16x8 aq[2];
#pragma unroll
    for (int s = 0; s < 2; ++s) {
        bf16x8 raw = *(const bf16x8*)(QKV + (size_t)(qw + l15) * QKVLD + h * DH + s * 32 + l4 * 8);
#pragma unroll
        for (int j = 0; j < 8; ++j) {
            float f = __builtin_bit_cast(float, ((unsigned int)(unsigned short)raw[j]) << 16) * QSC;
            raw[j] = __builtin_bit_cast(short, __float2bfloat16(f));
        }
        aq[s] = raw;
    }

    f32x4 o[4] = {};              // o[dt]: q = l4*4+reg, d = dt*16+l15
    float mrun = -1e30f, lrun = 0.f;
    const int cmax = CAUSAL ? qb : (S / 64 - 1);

    // stage chunk c into buffer b: linear slot n holds global slot (n&7)^(row&7)
#define STAGE(c, b)                                                                 \
    {                                                                               \
        const int kb2 = (c) * 64;                                                   \
        _Pragma("unroll")                                                           \
        for (int i = 0; i < 2; ++i) {                                               \
            int n = w * 128 + i * 64 + l;                                           \
            int row = n >> 3;                                                       \
            int sl = (n & 7) ^ (row & 7);                                           \
            gld16(Kh + ((size_t)h * S + kb2 + row) * 64 + sl * 8,                   \
                  lds + (b) * 16384 + w * 2048 + i * 1024);                         \
            gld16(Vt + ((size_t)(h * 64 + row)) * S + kb2 + sl * 8,                 \
                  lds + (b) * 16384 + 8192 + w * 2048 + i * 1024);                  \
        }                                                                           \
    }

    STAGE(0, 0);
    __syncthreads();

    int cur = 0;
    for (int c = 0; c <= cmax; ++c) {
        if (c < cmax) STAGE(c + 1, cur ^ 1);
        const char* kb = lds + cur * 16384;
        const char* vb = kb + 8192;
        const int kbase = c * 64;

        // S^T tiles: rows=keys, cols=q (ds_read_b128, swizzled)
        f32x4 st[4];
#pragma unroll
        for (int t = 0; t < 4; ++t) {
            f32x4 sacc = {0.f, 0.f, 0.f, 0.f};
#pragma unroll
            for (int s = 0; s < 2; ++s) {
                bf16x8 kf = *(const bf16x8*)(kb + (t * 16 + l15) * 128
                                             + (((s * 4 + l4) ^ (l15 & 7)) << 4));
                sacc = __builtin_amdgcn_mfma_f32_16x16x32_bf16(kf, aq[s], sacc, 0, 0, 0);
            }
            st[t] = sacc;
        }

        // mask + per-lane max (lane holds 16 values for q = l15)
        float mx = -1e30f;
#pragma unroll
        for (int t = 0; t < 4; ++t)
#pragma unroll
            for (int r = 0; r < 4; ++r) {
                float v = st[t][r];
                if (CAUSAL && c == cmax) {
                    int key = kbase + t * 16 + l4 * 4 + r;
                    if (key > qr) v = -1e30f;
                }
                st[t][r] = v;
                mx = fmaxf(mx, v);
            }
        mx = fmaxf(mx, __shfl_xor(mx, 16));
        mx = fmaxf(mx, __shfl_xor(mx, 32));

        // defer-max rescale (log2 units)
        if (__any(mx > mrun + 8.0f)) {
            float mnew = fmaxf(mrun, mx);
            float scl = exp2f(mrun - mnew);
            mrun = mnew;
            lrun *= scl;
#pragma unroll
            for (int j = 0; j < 4; ++j) {
                float sj = __shfl(scl, (l & 48) | (l4 * 4 + j));
#pragma unroll
                for (int dt = 0; dt < 4; ++dt) o[dt][j] *= sj;
            }
        }

        float ps = 0.f;
#pragma unroll
        for (int t = 0; t < 4; ++t) {
            float e0 = exp2f(st[t][0] - mrun);
            float e1 = exp2f(st[t][1] - mrun);
            float e2 = exp2f(st[t][2] - mrun);
            float e3 = exp2f(st[t][3] - mrun);
            ps += (e0 + e1) + (e2 + e3);
            unsigned int lo = (unsigned int)(unsigned short)__builtin_bit_cast(short, __float2bfloat16(e0))
                            | ((unsigned int)(unsigned short)__builtin_bit_cast(short, __float2bfloat16(e1)) << 16);
            unsigned int hi = (unsigned int)(unsigned short)__builtin_bit_cast(short, __float2bfloat16(e2))
                            | ((unsigned int)(unsigned short)__builtin_bit_cast(short, __float2bfloat16(e3)) << 16);
            uint2 pk; pk.x = lo; pk.y = hi;
            int byte = (l15 * 128 + t * 32 + l4 * 8) ^ ((l15 & 7) << 4);
            *(uint2*)(plds + byte) = pk;
        }
        ps += __shfl_xor(ps, 16);
        ps += __shfl_xor(ps, 32);
        lrun += ps;

        // PV: A-frag from plds, B-frag from staged Vt (swizzled ds_read)
        bf16x8 pf[2];
#pragma unroll
        for (int s = 0; s < 2; ++s) {
            int byte = (l15 * 128 + s * 64 + l4 * 16) ^ ((l15 & 7) << 4);
            pf[s] = *(const bf16x8*)(plds + byte);
        }
#pragma unroll
        for (int dt = 0; dt < 4; ++dt)
#pragma unroll
            for (int s = 0; s < 2; ++s) {
                bf16x8 vf = *(const bf16x8*)(vb + (dt * 16 + l15) * 128
                                             + (((s * 4 + l4) ^ (l15 & 7)) << 4));
                o[dt] = __builtin_amdgcn_mfma_f32_16x16x32_bf16(pf[s], vf, o[dt], 0, 0, 0);
            }

        __syncthreads();
        cur ^= 1;
    }
#undef STAGE

    float linv[4];
#pragma unroll
    for (int j = 0; j < 4; ++j)
        linv[j] = 1.f / __shfl(lrun, (l & 48) | (l4 * 4 + j));
#pragma unroll
    for (int dt = 0; dt < 4; ++dt)
#pragma unroll
        for (int j = 0; j < 4; ++j)
            O[(size_t)(qw + l4 * 4 + j) * D + h * DH + dt * 16 + l15] =
                __float2bfloat16(o[dt][j] * linv[j]);
}

// ---------------- residual add + layernorm (fp32, optional bf16 mirror) ----------------
__global__ __launch_bounds__(128)
void add_ln_kernel(const float* __restrict__ a, const float* __restrict__ b,
                   const float* __restrict__ g, const float* __restrict__ beta,
                   float* __restrict__ outF, bf16* __restrict__ outB)
{
    const int row = blockIdx.x;
    const int tid = threadIdx.x;
    float4 av = *(const float4*)&a[(size_t)row * D + tid * 4];
    float4 bv = *(const float4*)&b[(size_t)row * D + tid * 4];
    float4 s;
    s.x = av.x + bv.x; s.y = av.y + bv.y; s.z = av.z + bv.z; s.w = av.w + bv.w;
    float sum = s.x + s.y + s.z + s.w;
    float sq = s.x * s.x + s.y * s.y + s.z * s.z + s.w * s.w;
#pragma unroll
    for (int off = 32; off > 0; off >>= 1) {
        sum += __shfl_xor(sum, off);
        sq  += __shfl_xor(sq, off);
    }
    __shared__ float red[4];
    if ((tid & 63) == 0) { red[(tid >> 6) * 2] = sum; red[(tid >> 6) * 2 + 1] = sq; }
    __syncthreads();
    sum = red[0] + red[2];
    sq  = red[1] + red[3];
    float mu = sum / (float)D;
    float var = sq / (float)D - mu * mu;
    float rs = rsqrtf(var + 1e-6f);
    float4 gv = *(const float4*)&g[tid * 4];
    float4 bt = *(const float4*)&beta[tid * 4];
    float4 o;
    o.x = (s.x - mu) * rs * gv.x + bt.x;
    o.y = (s.y - mu) * rs * gv.y + bt.y;
    o.z = (s.z - mu) * rs * gv.z + bt.z;
    o.w = (s.w - mu) * rs * gv.w + bt.w;
    *(float4*)&outF[(size_t)row * D + tid * 4] = o;
    if (outB) {
        outB[(size_t)row * D + tid * 4 + 0] = __float2bfloat16(o.x);
        outB[(size_t)row * D + tid * 4 + 1] = __float2bfloat16(o.y);
        outB[(size_t)row * D + tid * 4 + 2] = __float2bfloat16(o.z);
        outB[(size_t)row * D + tid * 4 + 3] = __float2bfloat16(o.w);
    }
}

extern "C" void kernel_launch(void* const* d_in, const int* in_sizes, int n_in,
                              void* d_out, int out_size, void* d_ws, size_t ws_size,
                              hipStream_t stream)
{
    const float* x   = (const float*)d_in[0];
    const float* enc = (const float*)d_in[1];
    const float* a1w = (const float*)d_in[2];
    const float* a1b = (const float*)d_in[3];
    const float* a2w = (const float*)d_in[4];
    const float* a2b = (const float*)d_in[5];
    const float* fw1 = (const float*)d_in[6];
    const float* fb1 = (const float*)d_in[7];
    const float* fw2 = (const float*)d_in[8];
    const float* fb2 = (const float*)d_in[9];
    const float* lng = (const float*)d_in[10];
    const float* lnb = (const float*)d_in[11];
    float* out = (float*)d_out;

    char* wsb = (char*)d_ws;
    float* xb   = (float*)(wsb);                       // 4 MB
    float* ao   = (float*)(wsb + ((size_t)4 << 20));   // 4 MB
    bf16* xb16  = (bf16*)(wsb + ((size_t)8 << 20));    // 2 MB
    bf16* enc16 = (bf16*)(wsb + ((size_t)10 << 20));   // 2 MB
    bf16* att16 = (bf16*)(wsb + ((size_t)12 << 20));   // 2 MB
    bf16* qkv16 = (bf16*)(wsb + ((size_t)14 << 20));   // 6 MB [S][1536]
    bf16* vt16  = (bf16*)(wsb + ((size_t)20 << 20));   // 2 MB [512][S]
    bf16* ffh16 = qkv16;                               // 8 MB (overlaps vt16; disjoint lifetime)
    bf16* wts   = (bf16*)(wsb + ((size_t)22 << 20));   // 16 MB
    bf16* kh16  = (bf16*)(wsb + ((size_t)38 << 20));   // 2 MB [H][S][64]
    const size_t WCH = 1048576;
    const size_t DD = (size_t)D * D, DF = (size_t)D * F;

    // ---- weight prep (batched): transpose + bf16 ----
    transpose_cvt_b<<<dim3(8, 8, 8), 256, 0, stream>>>(a1w, wts,            D, D, DD, WCH, DD, 4);
    transpose_cvt_b<<<dim3(8, 8, 8), 256, 0, stream>>>(a2w, wts + 2 * WCH,  D, D, DD, WCH, DD, 4);
    transpose_cvt_b<<<dim3(8, 32, 2), 256, 0, stream>>>(fw1, wts + 4 * WCH, D, F, DF, WCH, 0, 1);
    transpose_cvt_b<<<dim3(32, 8, 2), 256, 0, stream>>>(fw2, wts + 6 * WCH, F, D, DF, WCH, 0, 1);
    cvt_kernel<<<(S * D + 255) / 256, 256, 0, stream>>>(enc, enc16, S * D);
    pos_add_kernel<<<(S * D + 255) / 256, 256, 0, stream>>>(x, xb, xb16);

    for (int l = 0; l < NLAYER; ++l) {
        const bf16* A1T = wts + (size_t)(0 + l) * WCH;
        const bf16* A2T = wts + (size_t)(2 + l) * WCH;
        const bf16* W1T = wts + (size_t)(4 + l) * WCH;
        const bf16* W2T = wts + (size_t)(6 + l) * WCH;
        const float* b1v = a1b + (size_t)l * 4 * D;
        const float* b2v = a2b + (size_t)l * 4 * D;

        // self-attention
        gemm_bf16<64, 64><<<dim3(24, 32), 256, 0, stream>>>(xb16, A1T, b1v, nullptr, qkv16, D, QKVLD, 0);
        kvt_kernel<<<dim3(32, 8), 256, 0, stream>>>(qkv16, kh16, vt16);
        attn_mfma6<1><<<dim3(H, S / 64), 256, 0, stream>>>(qkv16, kh16, vt16, att16);
        gemm_bf16<64, 64><<<dim3(8, 32), 256, 0, stream>>>(att16, A1T + 3 * DD, b1v + 3 * D, ao, nullptr, D, D, 0);
        add_ln_kernel<<<S, 128, 0, stream>>>(xb, ao, lng + (size_t)(l * 3 + 0) * D, lnb + (size_t)(l * 3 + 0) * D, xb, xb16);

        // cross-attention
        gemm_bf16<64, 64><<<dim3(8, 32), 256, 0, stream>>>(xb16, A2T, b2v, nullptr, qkv16, D, QKVLD, 0);
        gemm_bf16<64, 64><<<dim3(16, 32), 256, 0, stream>>>(enc16, A2T + DD, b2v + D, nullptr, qkv16 + D, D, QKVLD, 0);
        kvt_kernel<<<dim3(32, 8), 256, 0, stream>>>(qkv16, kh16, vt16);
        attn_mfma6<0><<<dim3(H, S / 64), 256, 0, stream>>>(qkv16, kh16, vt16, att16);
        gemm_bf16<64, 64><<<dim3(8, 32), 256, 0, stream>>>(att16, A2T + 3 * DD, b2v + 3 * D, ao, nullptr, D, D, 0);
        add_ln_kernel<<<S, 128, 0, stream>>>(xb, ao, lng + (size_t)(l * 3 + 1) * D, lnb + (size_t)(l * 3 + 1) * D, xb, xb16);

        // FFN
        gemm_bf16<64, 64><<<dim3(32, 32), 256, 0, stream>>>(xb16, W1T, fb1 + (size_t)l * F, nullptr, ffh16, D, F, 1);
        gemm_bf16<64, 64><<<dim3(8, 32), 256, 0, stream>>>(ffh16, W2T, fb2 + (size_t)l * D, ao, nullptr, F, D, 0);
        float* dstF = (l == NLAYER - 1) ? out : xb;
        bf16* dstB = (l == NLAYER - 1) ? nullptr : xb16;
        add_ln_kernel<<<S, 128, 0, stream>>>(xb, ao, lng + (size_t)(l * 3 + 2) * D, lnb + (size_t)(l * 3 + 2) * D, dstF, dstB);
    }
}

// Round 9
// 326.786 us; speedup vs baseline: 1.4133x; 1.0929x over previous
//
#include <hip/hip_runtime.h>
#include <hip/hip_bf16.h>
#include <math.h>

#define S 2048
#define D 512
#define H 8
#define DH 64
#define F 2048
#define NLAYER 2

typedef __attribute__((ext_vector_type(8))) short bf16x8;
typedef __attribute__((ext_vector_type(4))) float f32x4;
typedef __hip_bfloat16 bf16;

typedef __attribute__((address_space(3))) unsigned int lds_u32;
typedef __attribute__((address_space(1))) const unsigned int glb_u32;

__device__ __forceinline__ void gld16(const void* g, void* l) {
    __builtin_amdgcn_global_load_lds((glb_u32*)g, (lds_u32*)l, 16, 0, 0);
}

// ---------------- fused prep: pos-enc add (fp32+bf16) + enc convert ----------------
__global__ void prep_kernel(const float* __restrict__ x, const float* __restrict__ enc,
                            float* __restrict__ xbF, bf16* __restrict__ xbB,
                            bf16* __restrict__ encB) {
    int idx = blockIdx.x * blockDim.x + threadIdx.x;
    if (idx >= S * D) return;
    int s = idx / D;
    int j = idx % D;
    int jj = (j < D / 2) ? j : j - D / 2;
    float rate = expf(-(float)jj * (logf(10000.0f) / (float)(D / 2)));
    float ang = (float)s * rate;
    float pe = (j < D / 2) ? sinf(ang) : cosf(ang);
    float v = x[idx] + pe;
    xbF[idx] = v;
    xbB[idx] = __float2bfloat16(v);
    encB[idx] = __float2bfloat16(enc[idx]);
}

// ---------------- batched transpose + convert (weight prep) ----------------
__global__ __launch_bounds__(256)
void transpose_cvt_b(const float* __restrict__ in, bf16* __restrict__ out, int R, int C,
                     size_t inStride, size_t outL, size_t outM, int mpl)
{
    __shared__ float t[64][65];
    const int z = blockIdx.z;
    const float* src = in + (size_t)z * inStride;
    bf16* dst = out + (size_t)(z / mpl) * outL + (size_t)(z % mpl) * outM;
    const int rb = blockIdx.x * 64, cb = blockIdx.y * 64;
    for (int i = threadIdx.x; i < 4096; i += 256) {
        int r = i >> 6, c = i & 63;
        t[r][c] = src[(size_t)(rb + r) * C + cb + c];
    }
    __syncthreads();
    for (int i = threadIdx.x; i < 4096; i += 256) {
        int r = i >> 6, c = i & 63;
        dst[(size_t)(cb + r) * R + rb + c] = __float2bfloat16(t[c][r]);
    }
}

// ---------------- bf16 MFMA GEMM, 2-phase prefetch, BK-deep K-steps ----------------
// out = A[M,K] @ Bt[N,K]^T + bias.
// MODE 0: plain epilogue -> outF (fp32, ldc) and/or outB (bf16, ldc).
// MODE 1: attention pack -> cols [0,qn) to q16 [S][512]; [qn,qn+kn) to
//         kh[head][S][64]; rest to vt[d][S] (transposed via LDS bounce).
template<int BM, int BN, int BK, int MODE>
__global__ __launch_bounds__(256)
void gemm_bf16(const bf16* __restrict__ A, const bf16* __restrict__ Bt,
               const float* __restrict__ bias, float* __restrict__ outF,
               bf16* __restrict__ outB, int K, int ldc, int relu,
               bf16* __restrict__ q16, bf16* __restrict__ kh,
               bf16* __restrict__ vt, int qn, int kn)
{
    constexpr int MI = BM / 32, NJ = BN / 32;
    constexpr int SL = BK / 8;             // 16B slots per LDS row
    constexpr int KS = BK / 32;            // 32-k sub-steps per K-step
    constexpr int HALF = (BM + BN) * BK * 2;
    constexpr int IA = BM * SL / 256, IB = BN * SL / 256;
    __shared__ char lds[2 * HALF];
    const int tid = threadIdx.x;
    const int w = tid >> 6, l = tid & 63;
    const int l15 = l & 15, l4 = l >> 4;
    const int bm = blockIdx.y * BM, bn = blockIdx.x * BN;
    const int wr = (w >> 1) * (BM / 2), wc = (w & 1) * (BN / 2);

    f32x4 acc[MI][NJ] = {};

#define XV(row) ((BK == 64) ? ((row) & 7) : (((row) >> 1) & 3))
#define GSTAGE(k0, b)                                                          \
    {                                                                          \
        _Pragma("unroll")                                                      \
        for (int i = 0; i < IA; ++i) {                                         \
            int n = (w * IA + i) * 64 + l;                                     \
            int row = n / SL;                                                  \
            int sl = (n % SL) ^ XV(row);                                       \
            gld16(A + (size_t)(bm + row) * K + (k0) + sl * 8,                  \
                  lds + (b) * HALF + (w * IA + i) * 1024);                     \
        }                                                                      \
        _Pragma("unroll")                                                      \
        for (int i = 0; i < IB; ++i) {                                         \
            int n = (w * IB + i) * 64 + l;                                     \
            int row = n / SL;                                                  \
            int sl = (n % SL) ^ XV(row);                                       \
            gld16(Bt + (size_t)(bn + row) * K + (k0) + sl * 8,                 \
                  lds + (b) * HALF + BM * BK * 2 + (w * IB + i) * 1024);       \
        }                                                                      \
    }

    GSTAGE(0, 0);
    __syncthreads();
    int cur = 0;
    for (int k0 = 0; k0 < K; k0 += BK) {
        if (k0 + BK < K) GSTAGE(k0 + BK, cur ^ 1);
        const char* base = lds + cur * HALF;
        bf16x8 af[MI][KS], bfr[NJ][KS];
#pragma unroll
        for (int i = 0; i < MI; ++i) {
            int row = wr + i * 16 + l15;
#pragma unroll
            for (int s = 0; s < KS; ++s)
                af[i][s] = *(const bf16x8*)(base + row * (BK * 2)
                                            + (((s * 4 + l4) ^ XV(row)) << 4));
        }
#pragma unroll
        for (int j = 0; j < NJ; ++j) {
            int row = wc + j * 16 + l15;
#pragma unroll
            for (int s = 0; s < KS; ++s)
                bfr[j][s] = *(const bf16x8*)(base + BM * BK * 2 + row * (BK * 2)
                                             + (((s * 4 + l4) ^ XV(row)) << 4));
        }
#pragma unroll
        for (int s = 0; s < KS; ++s)
#pragma unroll
            for (int i = 0; i < MI; ++i)
#pragma unroll
                for (int j = 0; j < NJ; ++j)
                    acc[i][j] = __builtin_amdgcn_mfma_f32_16x16x32_bf16(af[i][s], bfr[j][s], acc[i][j], 0, 0, 0);
        __syncthreads();
        cur ^= 1;
    }
#undef GSTAGE
#undef XV

    if (MODE == 0) {
#pragma unroll
        for (int i = 0; i < MI; ++i)
#pragma unroll
            for (int j = 0; j < NJ; ++j)
#pragma unroll
                for (int q = 0; q < 4; ++q) {
                    int row = bm + wr + i * 16 + l4 * 4 + q;
                    int col = bn + wc + j * 16 + l15;
                    float v = acc[i][j][q] + bias[col];
                    if (relu) v = fmaxf(v, 0.f);
                    if (outF) outF[(size_t)row * ldc + col] = v;
                    if (outB) outB[(size_t)row * ldc + col] = __float2bfloat16(v);
                }
    } else {
        const int creg = (bn < qn) ? 0 : (bn < qn + kn ? 1 : 2);
        if (creg < 2) {
#pragma unroll
            for (int i = 0; i < MI; ++i)
#pragma unroll
                for (int j = 0; j < NJ; ++j)
#pragma unroll
                    for (int q = 0; q < 4; ++q) {
                        int row = bm + wr + i * 16 + l4 * 4 + q;
                        int col = bn + wc + j * 16 + l15;
                        float v = acc[i][j][q] + bias[col];
                        if (creg == 0) {
                            q16[(size_t)row * 512 + col] = __float2bfloat16(v);
                        } else {
                            int c2 = col - qn;
                            kh[((size_t)(c2 >> 6) * S + row) * 64 + (c2 & 63)] = __float2bfloat16(v);
                        }
                    }
        } else {
            // V region: bounce through LDS, write transposed vt[d][S]
            short* t = (short*)lds;
#pragma unroll
            for (int i = 0; i < MI; ++i)
#pragma unroll
                for (int j = 0; j < NJ; ++j)
#pragma unroll
                    for (int q = 0; q < 4; ++q) {
                        int r = wr + i * 16 + l4 * 4 + q;       // local row (s index)
                        int c = wc + j * 16 + l15;              // local col (d index)
                        float v = acc[i][j][q] + bias[bn + c];
                        t[r * 72 + c] = __builtin_bit_cast(short, __float2bfloat16(v));
                    }
            __syncthreads();
            const int dgb = bn - qn - kn;
            for (int i2 = tid; i2 < 512; i2 += 256) {
                int dl = i2 >> 3, s8 = (i2 & 7) * 8;
                bf16x8 v;
#pragma unroll
                for (int jj = 0; jj < 8; ++jj)
                    v[jj] = t[(s8 + jj) * 72 + dl];
                *(bf16x8*)(vt + (size_t)(dgb + dl) * S + bm + s8) = v;
            }
        }
    }
}

// ---------------- LDS-staged MFMA flash attention ----------------
// Block = 4 waves (256 thr) = one (head, 64-q-row tile); wave w owns q-rows
// qb*64 + w*16 .. +15 end-to-end. K (head-packed Kh) and V (d-major Vt)
// staged per 64-key chunk into LDS via bulk global_load_lds, double-buffered,
// one barrier/chunk. XOR swizzle both-sides (rule 21). Swapped QK^T
// (mfma(K,Q)); softmax log2-domain with pre-scaled Q; defer-max (THR=8).
// Grid (H, S/64): same-head blocks cluster for K/V L2 locality.
template<int CAUSAL>
__global__ __launch_bounds__(256)
void attn_mfma6(const bf16* __restrict__ Q, const bf16* __restrict__ Kh,
                const bf16* __restrict__ Vt, bf16* __restrict__ O)
{
    // [0,8192) Kbuf0 | [8192,16384) Vbuf0 | [16384,24576) Kbuf1 |
    // [24576,32768) Vbuf1 | [32768,40960) P tiles (2KB/wave)
    __shared__ char lds[40960];
    const int tid = threadIdx.x;
    const int w = tid >> 6, l = tid & 63;
    const int l15 = l & 15, l4 = l >> 4;
    const int h = blockIdx.x, qb = blockIdx.y;
    const int qw = qb * 64 + w * 16;
    const int qr = qw + l15;
    char* plds = lds + 32768 + w * 2048;

    // Q fragment from dense q16 [S][512], pre-scaled by 0.125 * log2(e)
    const float QSC = 0.1803368801f;
    bf16x8 aq[2];
#pragma unroll
    for (int s = 0; s < 2; ++s) {
        bf16x8 raw = *(const bf16x8*)(Q + (size_t)(qw + l15) * 512 + h * DH + s * 32 + l4 * 8);
#pragma unroll
        for (int j = 0; j < 8; ++j) {
            float f = __builtin_bit_cast(float, ((unsigned int)(unsigned short)raw[j]) << 16) * QSC;
            raw[j] = __builtin_bit_cast(short, __float2bfloat16(f));
        }
        aq[s] = raw;
    }

    f32x4 o[4] = {};              // o[dt]: q = l4*4+reg, d = dt*16+l15
    float mrun = -1e30f, lrun = 0.f;
    const int cmax = CAUSAL ? qb : (S / 64 - 1);

#define STAGE(c, b)                                                                 \
    {                                                                               \
        const int kb2 = (c) * 64;                                                   \
        _Pragma("unroll")                                                           \
        for (int i = 0; i < 2; ++i) {                                               \
            int n = w * 128 + i * 64 + l;                                           \
            int row = n >> 3;                                                       \
            int sl = (n & 7) ^ (row & 7);                                           \
            gld16(Kh + ((size_t)h * S + kb2 + row) * 64 + sl * 8,                   \
                  lds + (b) * 16384 + w * 2048 + i * 1024);                         \
            gld16(Vt + ((size_t)(h * 64 + row)) * S + kb2 + sl * 8,                 \
                  lds + (b) * 16384 + 8192 + w * 2048 + i * 1024);                  \
        }                                                                           \
    }

    STAGE(0, 0);
    __syncthreads();

    int cur = 0;
    for (int c = 0; c <= cmax; ++c) {
        if (c < cmax) STAGE(c + 1, cur ^ 1);
        const char* kb = lds + cur * 16384;
        const char* vb = kb + 8192;
        const int kbase = c * 64;

        f32x4 st[4];
#pragma unroll
        for (int t = 0; t < 4; ++t) {
            f32x4 sacc = {0.f, 0.f, 0.f, 0.f};
#pragma unroll
            for (int s = 0; s < 2; ++s) {
                bf16x8 kf = *(const bf16x8*)(kb + (t * 16 + l15) * 128
                                             + (((s * 4 + l4) ^ (l15 & 7)) << 4));
                sacc = __builtin_amdgcn_mfma_f32_16x16x32_bf16(kf, aq[s], sacc, 0, 0, 0);
            }
            st[t] = sacc;
        }

        float mx = -1e30f;
#pragma unroll
        for (int t = 0; t < 4; ++t)
#pragma unroll
            for (int r = 0; r < 4; ++r) {
                float v = st[t][r];
                if (CAUSAL && c == cmax) {
                    int key = kbase + t * 16 + l4 * 4 + r;
                    if (key > qr) v = -1e30f;
                }
                st[t][r] = v;
                mx = fmaxf(mx, v);
            }
        mx = fmaxf(mx, __shfl_xor(mx, 16));
        mx = fmaxf(mx, __shfl_xor(mx, 32));

        if (__any(mx > mrun + 8.0f)) {
            float mnew = fmaxf(mrun, mx);
            float scl = exp2f(mrun - mnew);
            mrun = mnew;
            lrun *= scl;
#pragma unroll
            for (int j = 0; j < 4; ++j) {
                float sj = __shfl(scl, (l & 48) | (l4 * 4 + j));
#pragma unroll
                for (int dt = 0; dt < 4; ++dt) o[dt][j] *= sj;
            }
        }

        float ps = 0.f;
#pragma unroll
        for (int t = 0; t < 4; ++t) {
            float e0 = exp2f(st[t][0] - mrun);
            float e1 = exp2f(st[t][1] - mrun);
            float e2 = exp2f(st[t][2] - mrun);
            float e3 = exp2f(st[t][3] - mrun);
            ps += (e0 + e1) + (e2 + e3);
            unsigned int lo = (unsigned int)(unsigned short)__builtin_bit_cast(short, __float2bfloat16(e0))
                            | ((unsigned int)(unsigned short)__builtin_bit_cast(short, __float2bfloat16(e1)) << 16);
            unsigned int hi = (unsigned int)(unsigned short)__builtin_bit_cast(short, __float2bfloat16(e2))
                            | ((unsigned int)(unsigned short)__builtin_bit_cast(short, __float2bfloat16(e3)) << 16);
            uint2 pk; pk.x = lo; pk.y = hi;
            int byte = (l15 * 128 + t * 32 + l4 * 8) ^ ((l15 & 7) << 4);
            *(uint2*)(plds + byte) = pk;
        }
        ps += __shfl_xor(ps, 16);
        ps += __shfl_xor(ps, 32);
        lrun += ps;

        bf16x8 pf[2];
#pragma unroll
        for (int s = 0; s < 2; ++s) {
            int byte = (l15 * 128 + s * 64 + l4 * 16) ^ ((l15 & 7) << 4);
            pf[s] = *(const bf16x8*)(plds + byte);
        }
#pragma unroll
        for (int dt = 0; dt < 4; ++dt)
#pragma unroll
            for (int s = 0; s < 2; ++s) {
                bf16x8 vf = *(const bf16x8*)(vb + (dt * 16 + l15) * 128
                                             + (((s * 4 + l4) ^ (l15 & 7)) << 4));
                o[dt] = __builtin_amdgcn_mfma_f32_16x16x32_bf16(pf[s], vf, o[dt], 0, 0, 0);
            }

        __syncthreads();
        cur ^= 1;
    }
#undef STAGE

    float linv[4];
#pragma unroll
    for (int j = 0; j < 4; ++j)
        linv[j] = 1.f / __shfl(lrun, (l & 48) | (l4 * 4 + j));
#pragma unroll
    for (int dt = 0; dt < 4; ++dt)
#pragma unroll
        for (int j = 0; j < 4; ++j)
            O[(size_t)(qw + l4 * 4 + j) * D + h * DH + dt * 16 + l15] =
                __float2bfloat16(o[dt][j] * linv[j]);
}

// ---------------- residual add + layernorm (fp32, optional bf16 mirror) ----------------
__global__ __launch_bounds__(128)
void add_ln_kernel(const float* __restrict__ a, const float* __restrict__ b,
                   const float* __restrict__ g, const float* __restrict__ beta,
                   float* __restrict__ outF, bf16* __restrict__ outB)
{
    const int row = blockIdx.x;
    const int tid = threadIdx.x;
    float4 av = *(const float4*)&a[(size_t)row * D + tid * 4];
    float4 bv = *(const float4*)&b[(size_t)row * D + tid * 4];
    float4 s;
    s.x = av.x + bv.x; s.y = av.y + bv.y; s.z = av.z + bv.z; s.w = av.w + bv.w;
    float sum = s.x + s.y + s.z + s.w;
    float sq = s.x * s.x + s.y * s.y + s.z * s.z + s.w * s.w;
#pragma unroll
    for (int off = 32; off > 0; off >>= 1) {
        sum += __shfl_xor(sum, off);
        sq  += __shfl_xor(sq, off);
    }
    __shared__ float red[4];
    if ((tid & 63) == 0) { red[(tid >> 6) * 2] = sum; red[(tid >> 6) * 2 + 1] = sq; }
    __syncthreads();
    sum = red[0] + red[2];
    sq  = red[1] + red[3];
    float mu = sum / (float)D;
    float var = sq / (float)D - mu * mu;
    float rs = rsqrtf(var + 1e-6f);
    float4 gv = *(const float4*)&g[tid * 4];
    float4 bt = *(const float4*)&beta[tid * 4];
    float4 o;
    o.x = (s.x - mu) * rs * gv.x + bt.x;
    o.y = (s.y - mu) * rs * gv.y + bt.y;
    o.z = (s.z - mu) * rs * gv.z + bt.z;
    o.w = (s.w - mu) * rs * gv.w + bt.w;
    *(float4*)&outF[(size_t)row * D + tid * 4] = o;
    if (outB) {
        outB[(size_t)row * D + tid * 4 + 0] = __float2bfloat16(o.x);
        outB[(size_t)row * D + tid * 4 + 1] = __float2bfloat16(o.y);
        outB[(size_t)row * D + tid * 4 + 2] = __float2bfloat16(o.z);
        outB[(size_t)row * D + tid * 4 + 3] = __float2bfloat16(o.w);
    }
}

extern "C" void kernel_launch(void* const* d_in, const int* in_sizes, int n_in,
                              void* d_out, int out_size, void* d_ws, size_t ws_size,
                              hipStream_t stream)
{
    const float* x   = (const float*)d_in[0];
    const float* enc = (const float*)d_in[1];
    const float* a1w = (const float*)d_in[2];
    const float* a1b = (const float*)d_in[3];
    const float* a2w = (const float*)d_in[4];
    const float* a2b = (const float*)d_in[5];
    const float* fw1 = (const float*)d_in[6];
    const float* fb1 = (const float*)d_in[7];
    const float* fw2 = (const float*)d_in[8];
    const float* fb2 = (const float*)d_in[9];
    const float* lng = (const float*)d_in[10];
    const float* lnb = (const float*)d_in[11];
    float* out = (float*)d_out;

    char* wsb = (char*)d_ws;
    float* xb   = (float*)(wsb);                       // 4 MB @0
    float* ao   = (float*)(wsb + ((size_t)4 << 20));   // 4 MB @4M
    bf16* xb16  = (bf16*)(wsb + ((size_t)8 << 20));    // 2 MB @8M
    bf16* enc16 = (bf16*)(wsb + ((size_t)10 << 20));   // 2 MB @10M
    bf16* att16 = (bf16*)(wsb + ((size_t)12 << 20));   // 2 MB @12M
    bf16* q16   = (bf16*)(wsb + ((size_t)14 << 20));   // 2 MB @14M
    bf16* kh16  = (bf16*)(wsb + ((size_t)16 << 20));   // 2 MB @16M
    bf16* vt16  = (bf16*)(wsb + ((size_t)18 << 20));   // 2 MB @18M
    bf16* ffh16 = att16;                               // 8 MB @12M (aliases attn bufs; disjoint lifetime)
    bf16* wts   = (bf16*)(wsb + ((size_t)20 << 20));   // 16 MB @20M
    const size_t WCH = 1048576;
    const size_t DD = (size_t)D * D, DF = (size_t)D * F;

    // ---- weight prep (batched): transpose + bf16 ----
    transpose_cvt_b<<<dim3(8, 8, 8), 256, 0, stream>>>(a1w, wts,            D, D, DD, WCH, DD, 4);
    transpose_cvt_b<<<dim3(8, 8, 8), 256, 0, stream>>>(a2w, wts + 2 * WCH,  D, D, DD, WCH, DD, 4);
    transpose_cvt_b<<<dim3(8, 32, 2), 256, 0, stream>>>(fw1, wts + 4 * WCH, D, F, DF, WCH, 0, 1);
    transpose_cvt_b<<<dim3(32, 8, 2), 256, 0, stream>>>(fw2, wts + 6 * WCH, F, D, DF, WCH, 0, 1);
    prep_kernel<<<(S * D + 255) / 256, 256, 0, stream>>>(x, enc, xb, xb16, enc16);

    for (int l = 0; l < NLAYER; ++l) {
        const bf16* A1T = wts + (size_t)(0 + l) * WCH;
        const bf16* A2T = wts + (size_t)(2 + l) * WCH;
        const bf16* W1T = wts + (size_t)(4 + l) * WCH;
        const bf16* W2T = wts + (size_t)(6 + l) * WCH;
        const float* b1v = a1b + (size_t)l * 4 * D;
        const float* b2v = a2b + (size_t)l * 4 * D;

        // self-attention: fused QKV GEMM writes q16/kh16/vt16 directly
        gemm_bf16<64, 64, 64, 1><<<dim3(24, 32), 256, 0, stream>>>(
            xb16, A1T, b1v, nullptr, nullptr, D, 0, 0, q16, kh16, vt16, 512, 512);
        attn_mfma6<1><<<dim3(H, S / 64), 256, 0, stream>>>(q16, kh16, vt16, att16);
        gemm_bf16<64, 64, 64, 0><<<dim3(8, 32), 256, 0, stream>>>(
            att16, A1T + 3 * DD, b1v + 3 * D, ao, nullptr, D, D, 0, nullptr, nullptr, nullptr, 0, 0);
        add_ln_kernel<<<S, 128, 0, stream>>>(xb, ao, lng + (size_t)(l * 3 + 0) * D, lnb + (size_t)(l * 3 + 0) * D, xb, xb16);

        // cross-attention
        gemm_bf16<64, 64, 64, 0><<<dim3(8, 32), 256, 0, stream>>>(
            xb16, A2T, b2v, nullptr, q16, D, 512, 0, nullptr, nullptr, nullptr, 0, 0);
        gemm_bf16<64, 64, 64, 1><<<dim3(16, 32), 256, 0, stream>>>(
            enc16, A2T + DD, b2v + D, nullptr, nullptr, D, 0, 0, q16, kh16, vt16, 0, 512);
        attn_mfma6<0><<<dim3(H, S / 64), 256, 0, stream>>>(q16, kh16, vt16, att16);
        gemm_bf16<64, 64, 64, 0><<<dim3(8, 32), 256, 0, stream>>>(
            att16, A2T + 3 * DD, b2v + 3 * D, ao, nullptr, D, D, 0, nullptr, nullptr, nullptr, 0, 0);
        add_ln_kernel<<<S, 128, 0, stream>>>(xb, ao, lng + (size_t)(l * 3 + 1) * D, lnb + (size_t)(l * 3 + 1) * D, xb, xb16);

        // FFN
        gemm_bf16<64, 64, 64, 0><<<dim3(32, 32), 256, 0, stream>>>(
            xb16, W1T, fb1 + (size_t)l * F, nullptr, ffh16, D, F, 1, nullptr, nullptr, nullptr, 0, 0);
        gemm_bf16<64, 64, 64, 0><<<dim3(8, 32), 256, 0, stream>>>(
            ffh16, W2T, fb2 + (size_t)l * D, ao, nullptr, F, D, 0, nullptr, nullptr, nullptr, 0, 0);
        float* dstF = (l == NLAYER - 1) ? out : xb;
        bf16* dstB = (l == NLAYER - 1) ? nullptr : xb16;
        add_ln_kernel<<<S, 128, 0, stream>>>(xb, ao, lng + (size_t)(l * 3 + 2) * D, lnb + (size_t)(l * 3 + 2) * D, dstF, dstB);
    }
}